// Round 15
// baseline (96.394 us; speedup 1.0000x reference)
//
#include <hip/hip_runtime.h>
#include <hip/hip_bf16.h>
#include <math.h>

#define DIM 512
#define NH 8
#define HD 64
#define TT 1024
#define CH 64      // chunks per (b,h) sequence
#define CL 16      // chunk length (CH*CL == TT)
#define EPSF 1e-5f
#define LN2F 0.69314718056f
#define LOG2EF 1.44269504089f

typedef unsigned short ushort_t;
typedef __attribute__((ext_vector_type(8))) short bf16x8;
typedef __attribute__((ext_vector_type(4))) float f32x4;

// raw gfx950 hardware transcendentals: v_exp_f32 = 2^x, v_log_f32 = log2(x)
__device__ __forceinline__ float fexp2(float x) { return __builtin_amdgcn_exp2f(x); }
__device__ __forceinline__ float flog2(float x) { return __builtin_amdgcn_logf(x); }

__device__ __forceinline__ ushort_t f2bf(float f) {
    union { float f; unsigned u; } v; v.f = f;
    unsigned r = v.u + 0x7FFFu + ((v.u >> 16) & 1u);
    return (ushort_t)(r >> 16);
}
__device__ __forceinline__ float bf2f(ushort_t h) {
    union { unsigned u; float f; } v; v.u = ((unsigned)h) << 16;
    return v.f;
}

// ---------------- fused cvt: x -> bf16 hi/lo  AND  weights -> bf16 [n][k] -----
#define NXB 1024   // (B*TT*DIM)/1024 with B=2
__launch_bounds__(256)
__global__ void k_cvt(const float* __restrict__ x, ushort_t* __restrict__ xh,
                      ushort_t* __restrict__ xl,
                      const float* __restrict__ wq, const float* __restrict__ wk,
                      const float* __restrict__ wv, const float* __restrict__ wo,
                      ushort_t* __restrict__ wTh, ushort_t* __restrict__ wTl,
                      ushort_t* __restrict__ wTo)
{
    if (blockIdx.x < NXB) {
        int i = (blockIdx.x * 256 + threadIdx.x) * 4;
        float4 v = *(const float4*)&x[i];
        ushort4 h, l;
        h.x = f2bf(v.x); l.x = f2bf(v.x - bf2f(h.x));
        h.y = f2bf(v.y); l.y = f2bf(v.y - bf2f(h.y));
        h.z = f2bf(v.z); l.z = f2bf(v.z - bf2f(h.z));
        h.w = f2bf(v.w); l.w = f2bf(v.w - bf2f(h.w));
        *(ushort4*)&xh[i] = h;
        *(ushort4*)&xl[i] = l;
        return;
    }
    const int bid = blockIdx.x - NXB;
    const int mat = bid >> 5;
    const int rest = bid & 31;
    const int ky = rest >> 3, nx = rest & 7;
    const float* w = (mat == 0) ? wq : (mat == 1) ? wk : (mat == 2) ? wv : wo;
    const int n  = nx * 64 + (threadIdx.x & 63);
    const int k0 = ky * 128 + (threadIdx.x >> 6) * 32;

    ushort_t hb[32], lb[32];
#pragma unroll
    for (int j = 0; j < 32; j++) {
        float v = w[(size_t)(k0 + j) * DIM + n];
        hb[j] = f2bf(v);
        lb[j] = f2bf(v - bf2f(hb[j]));
    }
    if (mat < 3) {
        ushort_t* dh = wTh + (size_t)mat * DIM * DIM + (size_t)n * DIM + k0;
        ushort_t* dl = wTl + (size_t)mat * DIM * DIM + (size_t)n * DIM + k0;
#pragma unroll
        for (int j = 0; j < 8; j++) {
            ushort4 th = { hb[4*j], hb[4*j+1], hb[4*j+2], hb[4*j+3] };
            ushort4 tl = { lb[4*j], lb[4*j+1], lb[4*j+2], lb[4*j+3] };
            *(ushort4*)&dh[4*j] = th;
            *(ushort4*)&dl[4*j] = tl;
        }
    } else {
        ushort_t* dh = wTo + (size_t)n * DIM + k0;
#pragma unroll
        for (int j = 0; j < 8; j++) {
            ushort4 th = { hb[4*j], hb[4*j+1], hb[4*j+2], hb[4*j+3] };
            *(ushort4*)&dh[4*j] = th;
        }
    }
}

// ---------------- Kernel 1: QKV projection, LDS-staged MFMA (hi/lo bf16) -----
// 2x2 wave tiling: wave (wr,wc) computes 32 rows x 32 cols (2x2 16x16 frags).
__launch_bounds__(256, 4)
__global__ void k_gemm_qkv(const ushort_t* __restrict__ xh, const ushort_t* __restrict__ xl,
                           const ushort_t* __restrict__ wTh, const ushort_t* __restrict__ wTl,
                           const float* __restrict__ bq, const float* __restrict__ bk,
                           const float* __restrict__ bv,
                           const float* __restrict__ lbeta, const float* __restrict__ ltemp,
                           float* __restrict__ Qf2, float* __restrict__ Kf,
                           float* __restrict__ Vv2)
{
    const int z = blockIdx.z, h = blockIdx.x;
    const int rowBase = blockIdx.y * 64;
    const int colBase = h * 64;
    const float* bias = (z == 0) ? bq : (z == 1) ? bk : bv;

    __shared__ __align__(16) ushort_t lds[2][4][2048];

    const int tid = threadIdx.x;
    const int l = tid & 63, wv = tid >> 6;
    const int m = l & 15, g = l >> 4;
    const int wr = wv & 1, wc = wv >> 1;

    const int rl = tid >> 2, cc = tid & 3;
    const int ci = ((rl >> 4) * 64 + cc * 16 + (rl & 15)) * 8;
    const ushort_t* gAh = xh + (size_t)(rowBase + rl) * DIM + cc * 8;
    const ushort_t* gAl = xl + (size_t)(rowBase + rl) * DIM + cc * 8;
    const ushort_t* gBh = wTh + (size_t)z * DIM * DIM + (size_t)(colBase + rl) * DIM + cc * 8;
    const ushort_t* gBl = wTl + (size_t)z * DIM * DIM + (size_t)(colBase + rl) * DIM + cc * 8;

    f32x4 acc[2][2] = { { {0,0,0,0}, {0,0,0,0} }, { {0,0,0,0}, {0,0,0,0} } };

    {
        bf16x8 a0 = *(const bf16x8*)gAh;
        bf16x8 a1 = *(const bf16x8*)gAl;
        bf16x8 b0 = *(const bf16x8*)gBh;
        bf16x8 b1 = *(const bf16x8*)gBl;
        *(bf16x8*)&lds[0][0][ci] = a0;
        *(bf16x8*)&lds[0][1][ci] = a1;
        *(bf16x8*)&lds[0][2][ci] = b0;
        *(bf16x8*)&lds[0][3][ci] = b1;
    }
    __syncthreads();

    for (int it = 0; it < 16; ++it) {
        const int cur = it & 1;
        bf16x8 nAh, nAl, nBh, nBl;
        if (it < 15) {
            const int K = (it + 1) * 32;
            nAh = *(const bf16x8*)(gAh + K);
            nAl = *(const bf16x8*)(gAl + K);
            nBh = *(const bf16x8*)(gBh + K);
            nBl = *(const bf16x8*)(gBl + K);
        }
        bf16x8 ah[2], al[2], bh[2], bl[2];
#pragma unroll
        for (int rf = 0; rf < 2; rf++) {
            ah[rf] = *(const bf16x8*)&lds[cur][0][((wr * 2 + rf) * 64 + l) * 8];
            al[rf] = *(const bf16x8*)&lds[cur][1][((wr * 2 + rf) * 64 + l) * 8];
        }
#pragma unroll
        for (int cf = 0; cf < 2; cf++) {
            bh[cf] = *(const bf16x8*)&lds[cur][2][((wc * 2 + cf) * 64 + l) * 8];
            bl[cf] = *(const bf16x8*)&lds[cur][3][((wc * 2 + cf) * 64 + l) * 8];
        }
#pragma unroll
        for (int rf = 0; rf < 2; rf++)
#pragma unroll
            for (int cf = 0; cf < 2; cf++) {
                acc[rf][cf] = __builtin_amdgcn_mfma_f32_16x16x32_bf16(ah[rf], bh[cf], acc[rf][cf], 0, 0, 0);
                acc[rf][cf] = __builtin_amdgcn_mfma_f32_16x16x32_bf16(al[rf], bh[cf], acc[rf][cf], 0, 0, 0);
                acc[rf][cf] = __builtin_amdgcn_mfma_f32_16x16x32_bf16(ah[rf], bl[cf], acc[rf][cf], 0, 0, 0);
            }
        if (it < 15) {
            const int nxt = cur ^ 1;
            *(bf16x8*)&lds[nxt][0][ci] = nAh;
            *(bf16x8*)&lds[nxt][1][ci] = nAl;
            *(bf16x8*)&lds[nxt][2][ci] = nBh;
            *(bf16x8*)&lds[nxt][3][ci] = nBl;
            __syncthreads();
        }
    }

    if (z == 2) {
#pragma unroll
        for (int rf = 0; rf < 2; rf++)
#pragma unroll
            for (int cf = 0; cf < 2; cf++) {
                int c = wc * 32 + cf * 16 + m;
                float bval = bias[colBase + c];
#pragma unroll
                for (int r = 0; r < 4; r++) {
                    int rr = rowBase + wr * 32 + rf * 16 + g * 4 + r;
                    int bb = rr >> 10, t = rr & (TT - 1);
                    Vv2[(((size_t)(bb * NH + h)) * TT + t) * HD + c] = (acc[rf][cf][r] + bval) * LOG2EF;
                }
            }
    } else {
        float beta = expf(lbeta[h]);
        float itemp = 1.0f / expf(ltemp[h]);
        float oscale = (z == 0) ? (LN2F / beta) : (1.0f / beta);
        float* __restrict__ dst = (z == 0) ? Qf2 : Kf;
#pragma unroll
        for (int rf = 0; rf < 2; rf++)
#pragma unroll
            for (int cf = 0; cf < 2; cf++) {
                int c = wc * 32 + cf * 16 + m;
                float bval = bias[colBase + c];
#pragma unroll
                for (int r = 0; r < 4; r++) {
                    int rr = rowBase + wr * 32 + rf * 16 + g * 4 + r;
                    int bb = rr >> 10, t = rr & (TT - 1);
                    float val = (acc[rf][cf][r] + bval) * itemp;
                    float zz = beta * val;
                    float sp = (fmaxf(zz, 0.f) + log1pf(expf(-fabsf(zz)))) * oscale;
                    dst[(((size_t)(bb * NH + h)) * TT + t) * HD + c] = sp;
                }
            }
    }
}

// ---------------- Kernel 2: per-chunk local sums (CL=16) ----------------
__launch_bounds__(256)
__global__ void k_chunk_reduce(const float* __restrict__ Kf, const float* __restrict__ Vv2,
                               float* __restrict__ aA, float* __restrict__ aD,
                               float* __restrict__ aCM)
{
    const int c = blockIdx.x >> 1, qh = blockIdx.x & 1;
    const int bh = blockIdx.z * NH + blockIdx.y;
    const int tid = threadIdx.x;

    __shared__ __align__(16) float sK[CL * HD];
    __shared__ __align__(16) float sV2[CL * HD];
    __shared__ __align__(16) float sM02[CL * HD];

    size_t base = ((size_t)bh * TT + (size_t)c * CL) * HD;
    const float4* K4 = (const float4*)(Kf + base);
    const float4* V4 = (const float4*)(Vv2 + base);
    {
        int f = tid;
        float4 kv = K4[f];
        ((float4*)sK)[f] = kv;
        float4 mm;
        mm.x = flog2(kv.x + EPSF); mm.y = flog2(kv.y + EPSF);
        mm.z = flog2(kv.z + EPSF); mm.w = flog2(kv.w + EPSF);
        ((float4*)sM02)[f] = mm;
        ((float4*)sV2)[f] = V4[f];
    }
    __syncthreads();

    const int p = tid & 63, qo = tid >> 6;
    const int q0 = qh * 32 + qo * 8;
    float A[8] = {};
    float AD = 0.f, cmx = 0.f;
    const bool doD = (qh == 0) && (tid < 64);

#pragma unroll
    for (int s = 0; s < CL; s++) {
        float vp = sV2[s * HD + p];
        float mp = sM02[s * HD + p];
        float4 ka = *(const float4*)&sK[s * HD + q0];
        float4 kb = *(const float4*)&sK[s * HD + q0 + 4];
        A[0] += fexp2(fmaf(vp, ka.x, mp));
        A[1] += fexp2(fmaf(vp, ka.y, mp));
        A[2] += fexp2(fmaf(vp, ka.z, mp));
        A[3] += fexp2(fmaf(vp, ka.w, mp));
        A[4] += fexp2(fmaf(vp, kb.x, mp));
        A[5] += fexp2(fmaf(vp, kb.y, mp));
        A[6] += fexp2(fmaf(vp, kb.z, mp));
        A[7] += fexp2(fmaf(vp, kb.w, mp));
        if (doD) {
            float kn = sK[s * HD + tid];
            float ke = kn + EPSF;
            AD += fexp2(kn * LOG2EF) * ke;
            cmx = fmaxf(cmx, ke);
        }
    }

    size_t abase = ((size_t)bh * CH + c) * 4096 + (size_t)p * HD + q0;
    float4 o0 = { A[0], A[1], A[2], A[3] };
    float4 o1 = { A[4], A[5], A[6], A[7] };
    *(float4*)&aA[abase] = o0;
    *(float4*)&aA[abase + 4] = o1;
    if (doD) {
        size_t dbase = ((size_t)bh * CH + c) * HD + tid;
        aD[dbase] = AD; aCM[dbase] = cmx;
    }
}

// ---------------- Kernel 3: exclusive scan of chunk aggregates (float4) -------
__global__ void k_scan_agg(float* __restrict__ aA, float* __restrict__ aD,
                           float* __restrict__ aCM, int BH)
{
    int idx = blockIdx.x * 256 + threadIdx.x;
    int nA4 = BH * 1024;          // BH*4096/4
    int nD4 = BH * 16;            // BH*64/4
    if (idx < nA4) {
        int bh = idx >> 10, pn4 = (idx & 1023) * 4;
        float4 Sr = {0.f, 0.f, 0.f, 0.f};
        for (int c = 0; c < CH; c++) {
            float* p = &aA[((size_t)bh * CH + c) * 4096 + pn4];
            float4 t = *(float4*)p;
            *(float4*)p = Sr;
            Sr.x += t.x; Sr.y += t.y; Sr.z += t.z; Sr.w += t.w;
        }
    } else if (idx < nA4 + nD4) {
        int i = idx - nA4; int bh = i >> 4, n4 = (i & 15) * 4;
        float4 Sr = {0.f, 0.f, 0.f, 0.f};
        for (int c = 0; c < CH; c++) {
            float* p = &aD[((size_t)bh * CH + c) * HD + n4];
            float4 t = *(float4*)p;
            *(float4*)p = Sr;
            Sr.x += t.x; Sr.y += t.y; Sr.z += t.z; Sr.w += t.w;
        }
    } else if (idx < nA4 + 2 * nD4) {
        int i = idx - nA4 - nD4; int bh = i >> 4, n4 = (i & 15) * 4;
        float4 r = {0.f, 0.f, 0.f, 0.f};
        for (int c = 0; c < CH; c++) {
            float* p = &aCM[((size_t)bh * CH + c) * HD + n4];
            float4 t = *(float4*)p;
            *(float4*)p = r;
            r.x = fmaxf(r.x, t.x); r.y = fmaxf(r.y, t.y);
            r.z = fmaxf(r.z, t.z); r.w = fmaxf(r.w, t.w);
        }
    }
}

// ---------------- Kernel 4: rescan + fused den + output Y -------------------
// 128 thr (2 waves), 1 chunk/block, grid 1024 -> 8 blocks/CU, 16 waves/CU.
// Thread owns 8p x 4q (contiguous quad): 7 x b128 per step serving 32 elems.
__launch_bounds__(128)
__global__ void k_chunk_out(const float* __restrict__ Kf, const float* __restrict__ Vv2,
                            const float* __restrict__ Qf2, const float* __restrict__ aA,
                            const float* __restrict__ aD, const float* __restrict__ aCM,
                            const float* __restrict__ lsharp, ushort_t* __restrict__ Ymb)
{
    const int c = blockIdx.x, hh = blockIdx.y, bb = blockIdx.z;
    const int bh = bb * NH + hh;
    const int tid = threadIdx.x;

    __shared__ __align__(16) float sK[CL * HD];
    __shared__ __align__(16) float sV2[CL * HD];
    __shared__ __align__(16) float sM02[CL * HD];
    __shared__ __align__(16) float sQ2[CL * HD];
    __shared__ float sC1[CL], sIV[CL];

    size_t base = ((size_t)bh * TT + (size_t)c * CL) * HD;
    const float4* K4 = (const float4*)(Kf + base);
    const float4* V4 = (const float4*)(Vv2 + base);
    const float4* Q4 = (const float4*)(Qf2 + base);
#pragma unroll
    for (int r = 0; r < 2; r++) {
        int f = tid + 128 * r;
        float4 kv = K4[f];
        ((float4*)sK)[f] = kv;
        float4 mm;
        mm.x = flog2(kv.x + EPSF); mm.y = flog2(kv.y + EPSF);
        mm.z = flog2(kv.z + EPSF); mm.w = flog2(kv.w + EPSF);
        ((float4*)sM02)[f] = mm;
        ((float4*)sV2)[f] = V4[f];
        ((float4*)sQ2)[f] = Q4[f];
    }
    __syncthreads();

    const int lane = tid & 63, w = tid >> 6;       // w in {0,1}
    const int g = lane >> 3, qil = lane & 7;
    const int qBase = w * 32 + qil * 4;
    const int p0 = g * 8;

    // A-state init from f32 prefix (float4 loads)
    float A[8][4];
    size_t abase = ((size_t)bh * CH + c) * 4096;
#pragma unroll
    for (int j = 0; j < 8; j++) {
        float4 av = *(const float4*)&aA[abase + (size_t)(p0 + j) * HD + qBase];
        A[j][0] = av.x; A[j][1] = av.y; A[j][2] = av.z; A[j][3] = av.w;
    }

    // ---- fused den phase (both waves maintain D-state; wave w reduces s&1==w)
    {
        size_t dofs = ((size_t)bh * CH + c) * HD + lane;
        float AD = aD[dofs], cmx = aCM[dofs];
#pragma unroll
        for (int s = 0; s < CL; s++) {
            float kn = sK[s * HD + lane];
            float ke = kn + EPSF;
            AD += fexp2(kn * LOG2EF) * ke;     // e^k * (k+eps)
            cmx = fmaxf(cmx, ke);
            if ((s & 1) == w) {
                float qn = sQ2[s * HD + lane];
                float t1 = qn * flog2(cmx);
                float t2 = qn * flog2(AD);
#pragma unroll
                for (int off = 1; off <= 32; off <<= 1) {
                    t1 += __shfl_xor(t1, off);
                    t2 += __shfl_xor(t2, off);
                }
                if (lane == 0) {
                    sC1[s] = t1;
                    sIV[s] = 1.0f / (t2 - t1 + EPSF);
                }
            }
        }
    }
    __syncthreads();

    const float sharp = expf(lsharp[hh]);
    const float invT = 1.0f / (float)TT;

#pragma unroll 4
    for (int s = 0; s < CL; s++) {
        float4 kq = *(const float4*)&sK[s * HD + qBase];
        float part[4] = {0.f, 0.f, 0.f, 0.f};
#pragma unroll
        for (int j4 = 0; j4 < 2; j4++) {
            float4 vv = *(const float4*)&sV2[s * HD + p0 + j4 * 4];
            float4 mm = *(const float4*)&sM02[s * HD + p0 + j4 * 4];
            float4 qv = *(const float4*)&sQ2[s * HD + p0 + j4 * 4];
#define STEPC(comp, jj) { \
            A[jj][0] += fexp2(fmaf(vv.comp, kq.x, mm.comp)); \
            A[jj][1] += fexp2(fmaf(vv.comp, kq.y, mm.comp)); \
            A[jj][2] += fexp2(fmaf(vv.comp, kq.z, mm.comp)); \
            A[jj][3] += fexp2(fmaf(vv.comp, kq.w, mm.comp)); \
            part[0] = fmaf(qv.comp, flog2(A[jj][0]), part[0]); \
            part[1] = fmaf(qv.comp, flog2(A[jj][1]), part[1]); \
            part[2] = fmaf(qv.comp, flog2(A[jj][2]), part[2]); \
            part[3] = fmaf(qv.comp, flog2(A[jj][3]), part[3]); }
            STEPC(x, j4 * 4 + 0)
            STEPC(y, j4 * 4 + 1)
            STEPC(z, j4 * 4 + 2)
            STEPC(w, j4 * 4 + 3)
#undef STEPC
        }
#pragma unroll
        for (int qi = 0; qi < 4; qi++) {
            part[qi] += __shfl_xor(part[qi], 8);
            part[qi] += __shfl_xor(part[qi], 16);
            part[qi] += __shfl_xor(part[qi], 32);
        }
        if (g == 0) {
            float c1v = sC1[s], iv = sIV[s];
            int tg = c * CL + s;
            float scale = (float)(tg + 1) * invT;
            ushort4 o;
            float y0 = (part[0] - c1v) * iv;
            float y1 = (part[1] - c1v) * iv;
            float y2 = (part[2] - c1v) * iv;
            float y3 = (part[3] - c1v) * iv;
            o.x = f2bf(copysignf(fexp2(sharp * flog2(fabsf(y0))), y0) * scale);
            o.y = f2bf(copysignf(fexp2(sharp * flog2(fabsf(y1))), y1) * scale);
            o.z = f2bf(copysignf(fexp2(sharp * flog2(fabsf(y2))), y2) * scale);
            o.w = f2bf(copysignf(fexp2(sharp * flog2(fabsf(y3))), y3) * scale);
            *(ushort4*)&Ymb[((size_t)(bb * TT + tg)) * DIM + hh * HD + qBase] = o;
        }
    }
}

// ---------------- Kernel 5: output projection, LDS-staged MFMA (bf16) ---------
__launch_bounds__(256, 4)
__global__ void k_gemm_out(const ushort_t* __restrict__ Ymb, const ushort_t* __restrict__ wTo,
                           const float* __restrict__ bias, float* __restrict__ out)
{
    const int colBase = blockIdx.x * 64;
    const int rowBase = blockIdx.y * 32;

    __shared__ __align__(16) ushort_t sA[2][1024];
    __shared__ __align__(16) ushort_t sB[2][2048];

    const int tid = threadIdx.x;
    const int l = tid & 63, wv = tid >> 6;
    const int m = l & 15, g = l >> 4;
    const int wr = wv & 1, wc = wv >> 1;

    const int rlB = tid >> 2, ccB = tid & 3;
    const int ciB = ((rlB >> 4) * 64 + ccB * 16 + (rlB & 15)) * 8;
    const ushort_t* gB = wTo + (size_t)(colBase + rlB) * DIM + ccB * 8;
    const int rlA = (tid & 127) >> 2, ccA = tid & 3;
    const int ciA = ((rlA >> 4) * 64 + ccA * 16 + (rlA & 15)) * 8;
    const ushort_t* gA = Ymb + (size_t)(rowBase + rlA) * DIM + ccA * 8;
    const bool doA = tid < 128;

    f32x4 acc[2] = { {0,0,0,0}, {0,0,0,0} };

    {
        bf16x8 b0 = *(const bf16x8*)gB;
        *(bf16x8*)&sB[0][ciB] = b0;
        if (doA) {
            bf16x8 a0 = *(const bf16x8*)gA;
            *(bf16x8*)&sA[0][ciA] = a0;
        }
    }
    __syncthreads();

    for (int it = 0; it < 16; ++it) {
        const int cur = it & 1;
        bf16x8 nA, nB;
        if (it < 15) {
            const int K = (it + 1) * 32;
            nB = *(const bf16x8*)(gB + K);
            if (doA) nA = *(const bf16x8*)(gA + K);
        }
        bf16x8 a = *(const bf16x8*)&sA[cur][(wr * 64 + l) * 8];
#pragma unroll
        for (int n = 0; n < 2; n++) {
            bf16x8 b = *(const bf16x8*)&sB[cur][((wc * 2 + n) * 64 + l) * 8];
            acc[n] = __builtin_amdgcn_mfma_f32_16x16x32_bf16(a, b, acc[n], 0, 0, 0);
        }
        if (it < 15) {
            const int nxt = cur ^ 1;
            *(bf16x8*)&sB[nxt][ciB] = nB;
            if (doA) *(bf16x8*)&sA[nxt][ciA] = nA;
            __syncthreads();
        }
    }

#pragma unroll
    for (int n = 0; n < 2; n++) {
        int c = colBase + wc * 32 + n * 16 + m;
        float bval = bias[c];
#pragma unroll
        for (int r = 0; r < 4; r++) {
            int rr = rowBase + wr * 16 + g * 4 + r;
            out[(size_t)rr * DIM + c] = acc[n][r] + bval;
        }
    }
}

extern "C" void kernel_launch(void* const* d_in, const int* in_sizes, int n_in,
                              void* d_out, int out_size, void* d_ws, size_t ws_size,
                              hipStream_t stream)
{
    const float* x  = (const float*)d_in[0];
    const float* wq = (const float*)d_in[1];
    const float* bq = (const float*)d_in[2];
    const float* wk = (const float*)d_in[3];
    const float* bk = (const float*)d_in[4];
    const float* wv = (const float*)d_in[5];
    const float* bv = (const float*)d_in[6];
    const float* wo = (const float*)d_in[7];
    const float* bo = (const float*)d_in[8];
    const float* lb = (const float*)d_in[9];
    const float* lt = (const float*)d_in[10];
    const float* ls = (const float*)d_in[11];

    const int B  = in_sizes[0] / (TT * DIM);   // 2
    const int BH = B * NH;                     // 16

    float* ws = (float*)d_ws;
    const size_t nQ = (size_t)BH * TT * HD;      // 1,048,576 floats
    float* Qf2 = ws;
    float* Kf  = Qf2 + nQ;
    float* Vv2 = Kf + nQ;
    float* region = Vv2 + nQ;                    // phase-aliased region

    // phase 1-2 (cvt + qkv): bf16 staging lives in region
    ushort_t* xh  = (ushort_t*)region;                                  // B*TT*DIM bf16
    ushort_t* xl  = xh + (size_t)B * TT * DIM;
    ushort_t* wTh = (ushort_t*)(region + (size_t)B * TT * DIM);         // 3*DIM*DIM bf16
    ushort_t* wTl = wTh + (size_t)3 * DIM * DIM;
    // phase 3+ : scan state overwrites the staging area
    ushort_t* Ymb = (ushort_t*)region;                                  // B*TT*DIM bf16
    float* aA  = region + (size_t)B * TT * DIM;                         // BH*CH*4096
    float* aD  = aA  + (size_t)BH * CH * 4096;
    float* aCM = aD  + (size_t)BH * CH * HD;
    ushort_t* wTo = (ushort_t*)(aCM + (size_t)BH * CH * HD);            // persists to end

    k_cvt<<<NXB + 128, 256, 0, stream>>>(x, xh, xl, wq, wk, wv, wo, wTh, wTl, wTo);

    dim3 g1(NH, (B * TT) / 64, 3);
    k_gemm_qkv<<<g1, 256, 0, stream>>>(xh, xl, wTh, wTl, bq, bk, bv, lb, lt, Qf2, Kf, Vv2);

    dim3 g2(CH * 2, NH, B);
    k_chunk_reduce<<<g2, 256, 0, stream>>>(Kf, Vv2, aA, aD, aCM);

    int ntot = BH * 1024 + 2 * BH * 16;
    k_scan_agg<<<(ntot + 255) / 256, 256, 0, stream>>>(aA, aD, aCM, BH);

    dim3 g4(CH, NH, B);
    k_chunk_out<<<g4, 128, 0, stream>>>(Kf, Vv2, Qf2, aA, aD, aCM, ls, Ymb);

    dim3 g6(DIM / 64, (B * TT) / 32);
    k_gemm_out<<<g6, 256, 0, stream>>>(Ymb, wTo, bo, (float*)d_out);
}

// Round 16
// 91.180 us; speedup vs baseline: 1.0572x; 1.0572x over previous
//
#include <hip/hip_runtime.h>
#include <hip/hip_bf16.h>
#include <math.h>

#define DIM 512
#define NH 8
#define HD 64
#define TT 1024
#define CH 64      // chunks per (b,h) sequence
#define CL 16      // chunk length (CH*CL == TT)
#define EPSF 1e-5f
#define LN2F 0.69314718056f
#define LOG2EF 1.44269504089f

typedef unsigned short ushort_t;
typedef __attribute__((ext_vector_type(8))) short bf16x8;
typedef __attribute__((ext_vector_type(4))) float f32x4;

// raw gfx950 hardware transcendentals: v_exp_f32 = 2^x, v_log_f32 = log2(x)
__device__ __forceinline__ float fexp2(float x) { return __builtin_amdgcn_exp2f(x); }
__device__ __forceinline__ float flog2(float x) { return __builtin_amdgcn_logf(x); }

__device__ __forceinline__ ushort_t f2bf(float f) {
    union { float f; unsigned u; } v; v.f = f;
    unsigned r = v.u + 0x7FFFu + ((v.u >> 16) & 1u);
    return (ushort_t)(r >> 16);
}
__device__ __forceinline__ float bf2f(ushort_t h) {
    union { unsigned u; float f; } v; v.u = ((unsigned)h) << 16;
    return v.f;
}

// ---------------- fused cvt: x -> bf16 hi/lo  AND  weights -> bf16 [n][k] -----
#define NXB 1024   // (B*TT*DIM)/1024 with B=2
__launch_bounds__(256)
__global__ void k_cvt(const float* __restrict__ x, ushort_t* __restrict__ xh,
                      ushort_t* __restrict__ xl,
                      const float* __restrict__ wq, const float* __restrict__ wk,
                      const float* __restrict__ wv, const float* __restrict__ wo,
                      ushort_t* __restrict__ wTh, ushort_t* __restrict__ wTl,
                      ushort_t* __restrict__ wTo)
{
    if (blockIdx.x < NXB) {
        int i = (blockIdx.x * 256 + threadIdx.x) * 4;
        float4 v = *(const float4*)&x[i];
        ushort4 h, l;
        h.x = f2bf(v.x); l.x = f2bf(v.x - bf2f(h.x));
        h.y = f2bf(v.y); l.y = f2bf(v.y - bf2f(h.y));
        h.z = f2bf(v.z); l.z = f2bf(v.z - bf2f(h.z));
        h.w = f2bf(v.w); l.w = f2bf(v.w - bf2f(h.w));
        *(ushort4*)&xh[i] = h;
        *(ushort4*)&xl[i] = l;
        return;
    }
    const int bid = blockIdx.x - NXB;
    const int mat = bid >> 5;
    const int rest = bid & 31;
    const int ky = rest >> 3, nx = rest & 7;
    const float* w = (mat == 0) ? wq : (mat == 1) ? wk : (mat == 2) ? wv : wo;
    const int n  = nx * 64 + (threadIdx.x & 63);
    const int k0 = ky * 128 + (threadIdx.x >> 6) * 32;

    ushort_t hb[32], lb[32];
#pragma unroll
    for (int j = 0; j < 32; j++) {
        float v = w[(size_t)(k0 + j) * DIM + n];
        hb[j] = f2bf(v);
        lb[j] = f2bf(v - bf2f(hb[j]));
    }
    if (mat < 3) {
        ushort_t* dh = wTh + (size_t)mat * DIM * DIM + (size_t)n * DIM + k0;
        ushort_t* dl = wTl + (size_t)mat * DIM * DIM + (size_t)n * DIM + k0;
#pragma unroll
        for (int j = 0; j < 8; j++) {
            ushort4 th = { hb[4*j], hb[4*j+1], hb[4*j+2], hb[4*j+3] };
            ushort4 tl = { lb[4*j], lb[4*j+1], lb[4*j+2], lb[4*j+3] };
            *(ushort4*)&dh[4*j] = th;
            *(ushort4*)&dl[4*j] = tl;
        }
    } else {
        ushort_t* dh = wTo + (size_t)n * DIM + k0;
#pragma unroll
        for (int j = 0; j < 8; j++) {
            ushort4 th = { hb[4*j], hb[4*j+1], hb[4*j+2], hb[4*j+3] };
            *(ushort4*)&dh[4*j] = th;
        }
    }
}

// ---------------- Kernel 1: QKV projection, LDS-staged MFMA (hi/lo bf16) -----
// 2x2 wave tiling: wave (wr,wc) computes 32 rows x 32 cols (2x2 16x16 frags).
__launch_bounds__(256, 4)
__global__ void k_gemm_qkv(const ushort_t* __restrict__ xh, const ushort_t* __restrict__ xl,
                           const ushort_t* __restrict__ wTh, const ushort_t* __restrict__ wTl,
                           const float* __restrict__ bq, const float* __restrict__ bk,
                           const float* __restrict__ bv,
                           const float* __restrict__ lbeta, const float* __restrict__ ltemp,
                           float* __restrict__ Qf2, float* __restrict__ Kf,
                           float* __restrict__ Vv2)
{
    const int z = blockIdx.z, h = blockIdx.x;
    const int rowBase = blockIdx.y * 64;
    const int colBase = h * 64;
    const float* bias = (z == 0) ? bq : (z == 1) ? bk : bv;

    __shared__ __align__(16) ushort_t lds[2][4][2048];

    const int tid = threadIdx.x;
    const int l = tid & 63, wv = tid >> 6;
    const int m = l & 15, g = l >> 4;
    const int wr = wv & 1, wc = wv >> 1;

    const int rl = tid >> 2, cc = tid & 3;
    const int ci = ((rl >> 4) * 64 + cc * 16 + (rl & 15)) * 8;
    const ushort_t* gAh = xh + (size_t)(rowBase + rl) * DIM + cc * 8;
    const ushort_t* gAl = xl + (size_t)(rowBase + rl) * DIM + cc * 8;
    const ushort_t* gBh = wTh + (size_t)z * DIM * DIM + (size_t)(colBase + rl) * DIM + cc * 8;
    const ushort_t* gBl = wTl + (size_t)z * DIM * DIM + (size_t)(colBase + rl) * DIM + cc * 8;

    f32x4 acc[2][2] = { { {0,0,0,0}, {0,0,0,0} }, { {0,0,0,0}, {0,0,0,0} } };

    {
        bf16x8 a0 = *(const bf16x8*)gAh;
        bf16x8 a1 = *(const bf16x8*)gAl;
        bf16x8 b0 = *(const bf16x8*)gBh;
        bf16x8 b1 = *(const bf16x8*)gBl;
        *(bf16x8*)&lds[0][0][ci] = a0;
        *(bf16x8*)&lds[0][1][ci] = a1;
        *(bf16x8*)&lds[0][2][ci] = b0;
        *(bf16x8*)&lds[0][3][ci] = b1;
    }
    __syncthreads();

    for (int it = 0; it < 16; ++it) {
        const int cur = it & 1;
        bf16x8 nAh, nAl, nBh, nBl;
        if (it < 15) {
            const int K = (it + 1) * 32;
            nAh = *(const bf16x8*)(gAh + K);
            nAl = *(const bf16x8*)(gAl + K);
            nBh = *(const bf16x8*)(gBh + K);
            nBl = *(const bf16x8*)(gBl + K);
        }
        bf16x8 ah[2], al[2], bh[2], bl[2];
#pragma unroll
        for (int rf = 0; rf < 2; rf++) {
            ah[rf] = *(const bf16x8*)&lds[cur][0][((wr * 2 + rf) * 64 + l) * 8];
            al[rf] = *(const bf16x8*)&lds[cur][1][((wr * 2 + rf) * 64 + l) * 8];
        }
#pragma unroll
        for (int cf = 0; cf < 2; cf++) {
            bh[cf] = *(const bf16x8*)&lds[cur][2][((wc * 2 + cf) * 64 + l) * 8];
            bl[cf] = *(const bf16x8*)&lds[cur][3][((wc * 2 + cf) * 64 + l) * 8];
        }
#pragma unroll
        for (int rf = 0; rf < 2; rf++)
#pragma unroll
            for (int cf = 0; cf < 2; cf++) {
                acc[rf][cf] = __builtin_amdgcn_mfma_f32_16x16x32_bf16(ah[rf], bh[cf], acc[rf][cf], 0, 0, 0);
                acc[rf][cf] = __builtin_amdgcn_mfma_f32_16x16x32_bf16(al[rf], bh[cf], acc[rf][cf], 0, 0, 0);
                acc[rf][cf] = __builtin_amdgcn_mfma_f32_16x16x32_bf16(ah[rf], bl[cf], acc[rf][cf], 0, 0, 0);
            }
        if (it < 15) {
            const int nxt = cur ^ 1;
            *(bf16x8*)&lds[nxt][0][ci] = nAh;
            *(bf16x8*)&lds[nxt][1][ci] = nAl;
            *(bf16x8*)&lds[nxt][2][ci] = nBh;
            *(bf16x8*)&lds[nxt][3][ci] = nBl;
            __syncthreads();
        }
    }

    if (z == 2) {
#pragma unroll
        for (int rf = 0; rf < 2; rf++)
#pragma unroll
            for (int cf = 0; cf < 2; cf++) {
                int c = wc * 32 + cf * 16 + m;
                float bval = bias[colBase + c];
#pragma unroll
                for (int r = 0; r < 4; r++) {
                    int rr = rowBase + wr * 32 + rf * 16 + g * 4 + r;
                    int bb = rr >> 10, t = rr & (TT - 1);
                    Vv2[(((size_t)(bb * NH + h)) * TT + t) * HD + c] = (acc[rf][cf][r] + bval) * LOG2EF;
                }
            }
    } else {
        float beta = expf(lbeta[h]);
        float itemp = 1.0f / expf(ltemp[h]);
        float oscale = (z == 0) ? (LN2F / beta) : (1.0f / beta);
        float* __restrict__ dst = (z == 0) ? Qf2 : Kf;
#pragma unroll
        for (int rf = 0; rf < 2; rf++)
#pragma unroll
            for (int cf = 0; cf < 2; cf++) {
                int c = wc * 32 + cf * 16 + m;
                float bval = bias[colBase + c];
#pragma unroll
                for (int r = 0; r < 4; r++) {
                    int rr = rowBase + wr * 32 + rf * 16 + g * 4 + r;
                    int bb = rr >> 10, t = rr & (TT - 1);
                    float val = (acc[rf][cf][r] + bval) * itemp;
                    float zz = beta * val;
                    float sp = (fmaxf(zz, 0.f) + log1pf(expf(-fabsf(zz)))) * oscale;
                    dst[(((size_t)(bb * NH + h)) * TT + t) * HD + c] = sp;
                }
            }
    }
}

// ---------------- Kernel 2: per-chunk local sums (CL=16) ----------------
__launch_bounds__(256)
__global__ void k_chunk_reduce(const float* __restrict__ Kf, const float* __restrict__ Vv2,
                               float* __restrict__ aA, float* __restrict__ aD,
                               float* __restrict__ aCM)
{
    const int c = blockIdx.x >> 1, qh = blockIdx.x & 1;
    const int bh = blockIdx.z * NH + blockIdx.y;
    const int tid = threadIdx.x;

    __shared__ __align__(16) float sK[CL * HD];
    __shared__ __align__(16) float sV2[CL * HD];
    __shared__ __align__(16) float sM02[CL * HD];

    size_t base = ((size_t)bh * TT + (size_t)c * CL) * HD;
    const float4* K4 = (const float4*)(Kf + base);
    const float4* V4 = (const float4*)(Vv2 + base);
    {
        int f = tid;
        float4 kv = K4[f];
        ((float4*)sK)[f] = kv;
        float4 mm;
        mm.x = flog2(kv.x + EPSF); mm.y = flog2(kv.y + EPSF);
        mm.z = flog2(kv.z + EPSF); mm.w = flog2(kv.w + EPSF);
        ((float4*)sM02)[f] = mm;
        ((float4*)sV2)[f] = V4[f];
    }
    __syncthreads();

    const int p = tid & 63, qo = tid >> 6;
    const int q0 = qh * 32 + qo * 8;
    float A[8] = {};
    float AD = 0.f, cmx = 0.f;
    const bool doD = (qh == 0) && (tid < 64);

#pragma unroll
    for (int s = 0; s < CL; s++) {
        float vp = sV2[s * HD + p];
        float mp = sM02[s * HD + p];
        float4 ka = *(const float4*)&sK[s * HD + q0];
        float4 kb = *(const float4*)&sK[s * HD + q0 + 4];
        A[0] += fexp2(fmaf(vp, ka.x, mp));
        A[1] += fexp2(fmaf(vp, ka.y, mp));
        A[2] += fexp2(fmaf(vp, ka.z, mp));
        A[3] += fexp2(fmaf(vp, ka.w, mp));
        A[4] += fexp2(fmaf(vp, kb.x, mp));
        A[5] += fexp2(fmaf(vp, kb.y, mp));
        A[6] += fexp2(fmaf(vp, kb.z, mp));
        A[7] += fexp2(fmaf(vp, kb.w, mp));
        if (doD) {
            float kn = sK[s * HD + tid];
            float ke = kn + EPSF;
            AD += fexp2(kn * LOG2EF) * ke;
            cmx = fmaxf(cmx, ke);
        }
    }

    size_t abase = ((size_t)bh * CH + c) * 4096 + (size_t)p * HD + q0;
    float4 o0 = { A[0], A[1], A[2], A[3] };
    float4 o1 = { A[4], A[5], A[6], A[7] };
    *(float4*)&aA[abase] = o0;
    *(float4*)&aA[abase + 4] = o1;
    if (doD) {
        size_t dbase = ((size_t)bh * CH + c) * HD + tid;
        aD[dbase] = AD; aCM[dbase] = cmx;
    }
}

// ---------------- Kernel 3: exclusive scan of chunk aggregates (float4) -------
__global__ void k_scan_agg(float* __restrict__ aA, float* __restrict__ aD,
                           float* __restrict__ aCM, int BH)
{
    int idx = blockIdx.x * 256 + threadIdx.x;
    int nA4 = BH * 1024;          // BH*4096/4
    int nD4 = BH * 16;            // BH*64/4
    if (idx < nA4) {
        int bh = idx >> 10, pn4 = (idx & 1023) * 4;
        float4 Sr = {0.f, 0.f, 0.f, 0.f};
        for (int c = 0; c < CH; c++) {
            float* p = &aA[((size_t)bh * CH + c) * 4096 + pn4];
            float4 t = *(float4*)p;
            *(float4*)p = Sr;
            Sr.x += t.x; Sr.y += t.y; Sr.z += t.z; Sr.w += t.w;
        }
    } else if (idx < nA4 + nD4) {
        int i = idx - nA4; int bh = i >> 4, n4 = (i & 15) * 4;
        float4 Sr = {0.f, 0.f, 0.f, 0.f};
        for (int c = 0; c < CH; c++) {
            float* p = &aD[((size_t)bh * CH + c) * HD + n4];
            float4 t = *(float4*)p;
            *(float4*)p = Sr;
            Sr.x += t.x; Sr.y += t.y; Sr.z += t.z; Sr.w += t.w;
        }
    } else if (idx < nA4 + 2 * nD4) {
        int i = idx - nA4 - nD4; int bh = i >> 4, n4 = (i & 15) * 4;
        float4 r = {0.f, 0.f, 0.f, 0.f};
        for (int c = 0; c < CH; c++) {
            float* p = &aCM[((size_t)bh * CH + c) * HD + n4];
            float4 t = *(float4*)p;
            *(float4*)p = r;
            r.x = fmaxf(r.x, t.x); r.y = fmaxf(r.y, t.y);
            r.z = fmaxf(r.z, t.z); r.w = fmaxf(r.w, t.w);
        }
    }
}

// ---------------- Kernel 4: rescan + fused den + output Y (q-split) ----------
// grid (CH*2, NH, B) = 2048 blocks; block handles 32 q's of one chunk.
// Thread owns 8p x 1q (8 elements) -> light VGPR state -> high occupancy.
// den phase identical per qh-pair (redundant, cheap).
__launch_bounds__(256)
__global__ void k_chunk_out(const float* __restrict__ Kf, const float* __restrict__ Vv2,
                            const float* __restrict__ Qf2, const float* __restrict__ aA,
                            const float* __restrict__ aD, const float* __restrict__ aCM,
                            const float* __restrict__ lsharp, ushort_t* __restrict__ Ymb)
{
    const int c = blockIdx.x >> 1, qh = blockIdx.x & 1;
    const int hh = blockIdx.y, bb = blockIdx.z;
    const int bh = bb * NH + hh;
    const int tid = threadIdx.x;

    __shared__ __align__(16) float sK[CL * HD];
    __shared__ __align__(16) float sV2[CL * HD];
    __shared__ __align__(16) float sM02[CL * HD];
    __shared__ __align__(16) float sQ2[CL * HD];
    __shared__ float sC1[CL], sIV[CL];

    size_t base = ((size_t)bh * TT + (size_t)c * CL) * HD;
    const float4* K4 = (const float4*)(Kf + base);
    const float4* V4 = (const float4*)(Vv2 + base);
    const float4* Q4 = (const float4*)(Qf2 + base);
    {
        int f = tid;
        float4 kv = K4[f];
        ((float4*)sK)[f] = kv;
        float4 mm;
        mm.x = flog2(kv.x + EPSF); mm.y = flog2(kv.y + EPSF);
        mm.z = flog2(kv.z + EPSF); mm.w = flog2(kv.w + EPSF);
        ((float4*)sM02)[f] = mm;
        ((float4*)sV2)[f] = V4[f];
        ((float4*)sQ2)[f] = Q4[f];
    }
    __syncthreads();

    const int lane = tid & 63, w = tid >> 6;
    const int g = lane >> 3, qil = lane & 7;
    const int qA = qh * 32 + w * 8 + qil;
    const int p0 = g * 8;

    // A-state init (8 elements only)
    float A[8];
    size_t abase = ((size_t)bh * CH + c) * 4096;
#pragma unroll
    for (int j = 0; j < 8; j++)
        A[j] = aA[abase + (size_t)(p0 + j) * HD + qA];

    // ---- fused den phase (4 waves maintain D-state; wave w reduces s&3==w) ----
    {
        size_t dofs = ((size_t)bh * CH + c) * HD + lane;
        float AD = aD[dofs], cmx = aCM[dofs];
#pragma unroll
        for (int s = 0; s < CL; s++) {
            float kn = sK[s * HD + lane];
            float ke = kn + EPSF;
            AD += fexp2(kn * LOG2EF) * ke;     // e^k * (k+eps)
            cmx = fmaxf(cmx, ke);
            if ((s & 3) == w) {
                float qn = sQ2[s * HD + lane];
                float t1 = qn * flog2(cmx);
                float t2 = qn * flog2(AD);
#pragma unroll
                for (int off = 1; off <= 32; off <<= 1) {
                    t1 += __shfl_xor(t1, off);
                    t2 += __shfl_xor(t2, off);
                }
                if (lane == 0) {
                    sC1[s] = t1;
                    sIV[s] = 1.0f / (t2 - t1 + EPSF);
                }
            }
        }
    }
    __syncthreads();

    const float sharp = expf(lsharp[hh]);
    const float invT = 1.0f / (float)TT;

#pragma unroll 4
    for (int s = 0; s < CL; s++) {
        float kqA = sK[s * HD + qA];
        float pA0 = 0.f, pA1 = 0.f;
#pragma unroll
        for (int j4 = 0; j4 < 2; j4++) {
            float4 vv = *(const float4*)&sV2[s * HD + p0 + j4 * 4];
            float4 mm = *(const float4*)&sM02[s * HD + p0 + j4 * 4];
            float4 qv = *(const float4*)&sQ2[s * HD + p0 + j4 * 4];
#define STEP(comp, jj, PA) { \
            A[jj] += fexp2(fmaf(vv.comp, kqA, mm.comp)); \
            PA = fmaf(qv.comp, flog2(A[jj]), PA); }
            STEP(x, j4 * 4 + 0, pA0)
            STEP(y, j4 * 4 + 1, pA1)
            STEP(z, j4 * 4 + 2, pA0)
            STEP(w, j4 * 4 + 3, pA1)
#undef STEP
        }
        float partA = pA0 + pA1;
        partA += __shfl_xor(partA, 8);
        partA += __shfl_xor(partA, 16);
        partA += __shfl_xor(partA, 32);

        if (g == 0) {
            float c1v = sC1[s], iv = sIV[s];
            int tg = c * CL + s;
            float scale = (float)(tg + 1) * invT;
            float yA = (partA - c1v) * iv;
            float oA = copysignf(fexp2(sharp * flog2(fabsf(yA))), yA) * scale;
            Ymb[((size_t)(bb * TT + tg)) * DIM + hh * HD + qA] = f2bf(oA);
        }
    }
}

// ---------------- Kernel 5: output projection, LDS-staged MFMA (bf16) ---------
__launch_bounds__(256, 4)
__global__ void k_gemm_out(const ushort_t* __restrict__ Ymb, const ushort_t* __restrict__ wTo,
                           const float* __restrict__ bias, float* __restrict__ out)
{
    const int colBase = blockIdx.x * 64;
    const int rowBase = blockIdx.y * 32;

    __shared__ __align__(16) ushort_t sA[2][1024];
    __shared__ __align__(16) ushort_t sB[2][2048];

    const int tid = threadIdx.x;
    const int l = tid & 63, wv = tid >> 6;
    const int m = l & 15, g = l >> 4;
    const int wr = wv & 1, wc = wv >> 1;

    const int rlB = tid >> 2, ccB = tid & 3;
    const int ciB = ((rlB >> 4) * 64 + ccB * 16 + (rlB & 15)) * 8;
    const ushort_t* gB = wTo + (size_t)(colBase + rlB) * DIM + ccB * 8;
    const int rlA = (tid & 127) >> 2, ccA = tid & 3;
    const int ciA = ((rlA >> 4) * 64 + ccA * 16 + (rlA & 15)) * 8;
    const ushort_t* gA = Ymb + (size_t)(rowBase + rlA) * DIM + ccA * 8;
    const bool doA = tid < 128;

    f32x4 acc[2] = { {0,0,0,0}, {0,0,0,0} };

    {
        bf16x8 b0 = *(const bf16x8*)gB;
        *(bf16x8*)&sB[0][ciB] = b0;
        if (doA) {
            bf16x8 a0 = *(const bf16x8*)gA;
            *(bf16x8*)&sA[0][ciA] = a0;
        }
    }
    __syncthreads();

    for (int it = 0; it < 16; ++it) {
        const int cur = it & 1;
        bf16x8 nA, nB;
        if (it < 15) {
            const int K = (it + 1) * 32;
            nB = *(const bf16x8*)(gB + K);
            if (doA) nA = *(const bf16x8*)(gA + K);
        }
        bf16x8 a = *(const bf16x8*)&sA[cur][(wr * 64 + l) * 8];
#pragma unroll
        for (int n = 0; n < 2; n++) {
            bf16x8 b = *(const bf16x8*)&sB[cur][((wc * 2 + n) * 64 + l) * 8];
            acc[n] = __builtin_amdgcn_mfma_f32_16x16x32_bf16(a, b, acc[n], 0, 0, 0);
        }
        if (it < 15) {
            const int nxt = cur ^ 1;
            *(bf16x8*)&sB[nxt][ciB] = nB;
            if (doA) *(bf16x8*)&sA[nxt][ciA] = nA;
            __syncthreads();
        }
    }

#pragma unroll
    for (int n = 0; n < 2; n++) {
        int c = colBase + wc * 32 + n * 16 + m;
        float bval = bias[c];
#pragma unroll
        for (int r = 0; r < 4; r++) {
            int rr = rowBase + wr * 16 + g * 4 + r;
            out[(size_t)rr * DIM + c] = acc[n][r] + bval;
        }
    }
}

extern "C" void kernel_launch(void* const* d_in, const int* in_sizes, int n_in,
                              void* d_out, int out_size, void* d_ws, size_t ws_size,
                              hipStream_t stream)
{
    const float* x  = (const float*)d_in[0];
    const float* wq = (const float*)d_in[1];
    const float* bq = (const float*)d_in[2];
    const float* wk = (const float*)d_in[3];
    const float* bk = (const float*)d_in[4];
    const float* wv = (const float*)d_in[5];
    const float* bv = (const float*)d_in[6];
    const float* wo = (const float*)d_in[7];
    const float* bo = (const float*)d_in[8];
    const float* lb = (const float*)d_in[9];
    const float* lt = (const float*)d_in[10];
    const float* ls = (const float*)d_in[11];

    const int B  = in_sizes[0] / (TT * DIM);   // 2
    const int BH = B * NH;                     // 16

    float* ws = (float*)d_ws;
    const size_t nQ = (size_t)BH * TT * HD;      // 1,048,576 floats
    float* Qf2 = ws;
    float* Kf  = Qf2 + nQ;
    float* Vv2 = Kf + nQ;
    float* region = Vv2 + nQ;                    // phase-aliased region

    // phase 1-2 (cvt + qkv): bf16 staging lives in region
    ushort_t* xh  = (ushort_t*)region;                                  // B*TT*DIM bf16
    ushort_t* xl  = xh + (size_t)B * TT * DIM;
    ushort_t* wTh = (ushort_t*)(region + (size_t)B * TT * DIM);         // 3*DIM*DIM bf16
    ushort_t* wTl = wTh + (size_t)3 * DIM * DIM;
    // phase 3+ : scan state overwrites the staging area
    ushort_t* Ymb = (ushort_t*)region;                                  // B*TT*DIM bf16
    float* aA  = region + (size_t)B * TT * DIM;                         // BH*CH*4096
    float* aD  = aA  + (size_t)BH * CH * 4096;
    float* aCM = aD  + (size_t)BH * CH * HD;
    ushort_t* wTo = (ushort_t*)(aCM + (size_t)BH * CH * HD);            // persists to end

    k_cvt<<<NXB + 128, 256, 0, stream>>>(x, xh, xl, wq, wk, wv, wo, wTh, wTl, wTo);

    dim3 g1(NH, (B * TT) / 64, 3);
    k_gemm_qkv<<<g1, 256, 0, stream>>>(xh, xl, wTh, wTl, bq, bk, bv, lb, lt, Qf2, Kf, Vv2);

    dim3 g2(CH * 2, NH, B);
    k_chunk_reduce<<<g2, 256, 0, stream>>>(Kf, Vv2, aA, aD, aCM);

    int ntot = BH * 1024 + 2 * BH * 16;
    k_scan_agg<<<(ntot + 255) / 256, 256, 0, stream>>>(aA, aD, aCM, BH);

    dim3 g4(CH * 2, NH, B);
    k_chunk_out<<<g4, 256, 0, stream>>>(Kf, Vv2, Qf2, aA, aD, aCM, ls, Ymb);

    dim3 g6(DIM / 64, (B * TT) / 32);
    k_gemm_out<<<g6, 256, 0, stream>>>(Ymb, wTo, bo, (float*)d_out);
}

// Round 17
// 90.364 us; speedup vs baseline: 1.0667x; 1.0090x over previous
//
#include <hip/hip_runtime.h>
#include <hip/hip_bf16.h>
#include <math.h>

#define DIM 512
#define NH 8
#define HD 64
#define TT 1024
#define CH 64      // chunks per (b,h) sequence
#define CL 16      // chunk length (CH*CL == TT)
#define EPSF 1e-5f
#define LN2F 0.69314718056f
#define LOG2EF 1.44269504089f

typedef unsigned short ushort_t;
typedef __attribute__((ext_vector_type(8))) short bf16x8;
typedef __attribute__((ext_vector_type(4))) float f32x4;

// raw gfx950 hardware transcendentals: v_exp_f32 = 2^x, v_log_f32 = log2(x)
__device__ __forceinline__ float fexp2(float x) { return __builtin_amdgcn_exp2f(x); }
__device__ __forceinline__ float flog2(float x) { return __builtin_amdgcn_logf(x); }

__device__ __forceinline__ ushort_t f2bf(float f) {
    union { float f; unsigned u; } v; v.f = f;
    unsigned r = v.u + 0x7FFFu + ((v.u >> 16) & 1u);
    return (ushort_t)(r >> 16);
}
__device__ __forceinline__ float bf2f(ushort_t h) {
    union { unsigned u; float f; } v; v.u = ((unsigned)h) << 16;
    return v.f;
}

// ---------------- cvt: weights -> transposed bf16 [n][k] (weights only) -------
// grid (8 n-tiles, 4 k-tiles, 4 matrices), 256 thr.
__launch_bounds__(256)
__global__ void k_cvt_w(const float* __restrict__ wq, const float* __restrict__ wk,
                        const float* __restrict__ wv, const float* __restrict__ wo,
                        ushort_t* __restrict__ wTh, ushort_t* __restrict__ wTl,
                        ushort_t* __restrict__ wTo)
{
    const int mat = blockIdx.z;
    const float* w = (mat == 0) ? wq : (mat == 1) ? wk : (mat == 2) ? wv : wo;
    const int n  = blockIdx.x * 64 + (threadIdx.x & 63);
    const int k0 = blockIdx.y * 128 + (threadIdx.x >> 6) * 32;

    ushort_t hb[32], lb[32];
#pragma unroll
    for (int j = 0; j < 32; j++) {
        float v = w[(size_t)(k0 + j) * DIM + n];
        hb[j] = f2bf(v);
        lb[j] = f2bf(v - bf2f(hb[j]));
    }
    if (mat < 3) {
        ushort_t* dh = wTh + (size_t)mat * DIM * DIM + (size_t)n * DIM + k0;
        ushort_t* dl = wTl + (size_t)mat * DIM * DIM + (size_t)n * DIM + k0;
#pragma unroll
        for (int j = 0; j < 8; j++) {
            ushort4 th = { hb[4*j], hb[4*j+1], hb[4*j+2], hb[4*j+3] };
            ushort4 tl = { lb[4*j], lb[4*j+1], lb[4*j+2], lb[4*j+3] };
            *(ushort4*)&dh[4*j] = th;
            *(ushort4*)&dl[4*j] = tl;
        }
    } else {
        ushort_t* dh = wTo + (size_t)n * DIM + k0;
#pragma unroll
        for (int j = 0; j < 8; j++) {
            ushort4 th = { hb[4*j], hb[4*j+1], hb[4*j+2], hb[4*j+3] };
            *(ushort4*)&dh[4*j] = th;
        }
    }
}

// ---------------- Kernel 1: QKV projection, LDS-staged MFMA (hi/lo bf16) -----
// 2x2 wave tiling; x read directly as f32, hi/lo split in staging (bit-identical
// to the old cvt path; same staged bytes: 1 f32 == 2 bf16).
__launch_bounds__(256, 4)
__global__ void k_gemm_qkv(const float* __restrict__ x,
                           const ushort_t* __restrict__ wTh, const ushort_t* __restrict__ wTl,
                           const float* __restrict__ bq, const float* __restrict__ bk,
                           const float* __restrict__ bv,
                           const float* __restrict__ lbeta, const float* __restrict__ ltemp,
                           float* __restrict__ Qf2, float* __restrict__ Kf,
                           float* __restrict__ Vv2)
{
    const int z = blockIdx.z, h = blockIdx.x;
    const int rowBase = blockIdx.y * 64;
    const int colBase = h * 64;
    const float* bias = (z == 0) ? bq : (z == 1) ? bk : bv;

    __shared__ __align__(16) ushort_t lds[2][4][2048];

    const int tid = threadIdx.x;
    const int l = tid & 63, wv = tid >> 6;
    const int m = l & 15, g = l >> 4;
    const int wr = wv & 1, wc = wv >> 1;

    const int rl = tid >> 2, cc = tid & 3;
    const int ci = ((rl >> 4) * 64 + cc * 16 + (rl & 15)) * 8;
    const float* gA = x + (size_t)(rowBase + rl) * DIM + cc * 8;
    const ushort_t* gBh = wTh + (size_t)z * DIM * DIM + (size_t)(colBase + rl) * DIM + cc * 8;
    const ushort_t* gBl = wTl + (size_t)z * DIM * DIM + (size_t)(colBase + rl) * DIM + cc * 8;

#define CVTHL(AH, AL, V0, V1) { \
    float xv_[8] = {V0.x, V0.y, V0.z, V0.w, V1.x, V1.y, V1.z, V1.w}; \
    _Pragma("unroll") \
    for (int j_ = 0; j_ < 8; j_++) { \
        ushort_t h_ = f2bf(xv_[j_]); \
        AH[j_] = (short)h_; \
        AL[j_] = (short)f2bf(xv_[j_] - bf2f(h_)); } }

    f32x4 acc[2][2] = { { {0,0,0,0}, {0,0,0,0} }, { {0,0,0,0}, {0,0,0,0} } };

    {
        float4 v0 = *(const float4*)(gA);
        float4 v1 = *(const float4*)(gA + 4);
        bf16x8 b0 = *(const bf16x8*)gBh;
        bf16x8 b1 = *(const bf16x8*)gBl;
        bf16x8 a0, a1;
        CVTHL(a0, a1, v0, v1)
        *(bf16x8*)&lds[0][0][ci] = a0;
        *(bf16x8*)&lds[0][1][ci] = a1;
        *(bf16x8*)&lds[0][2][ci] = b0;
        *(bf16x8*)&lds[0][3][ci] = b1;
    }
    __syncthreads();

    for (int it = 0; it < 16; ++it) {
        const int cur = it & 1;
        float4 nv0, nv1;
        bf16x8 nBh, nBl;
        if (it < 15) {
            const int K = (it + 1) * 32;
            nv0 = *(const float4*)(gA + K);
            nv1 = *(const float4*)(gA + K + 4);
            nBh = *(const bf16x8*)(gBh + K);
            nBl = *(const bf16x8*)(gBl + K);
        }
        bf16x8 ah[2], al[2], bh[2], bl[2];
#pragma unroll
        for (int rf = 0; rf < 2; rf++) {
            ah[rf] = *(const bf16x8*)&lds[cur][0][((wr * 2 + rf) * 64 + l) * 8];
            al[rf] = *(const bf16x8*)&lds[cur][1][((wr * 2 + rf) * 64 + l) * 8];
        }
#pragma unroll
        for (int cf = 0; cf < 2; cf++) {
            bh[cf] = *(const bf16x8*)&lds[cur][2][((wc * 2 + cf) * 64 + l) * 8];
            bl[cf] = *(const bf16x8*)&lds[cur][3][((wc * 2 + cf) * 64 + l) * 8];
        }
#pragma unroll
        for (int rf = 0; rf < 2; rf++)
#pragma unroll
            for (int cf = 0; cf < 2; cf++) {
                acc[rf][cf] = __builtin_amdgcn_mfma_f32_16x16x32_bf16(ah[rf], bh[cf], acc[rf][cf], 0, 0, 0);
                acc[rf][cf] = __builtin_amdgcn_mfma_f32_16x16x32_bf16(al[rf], bh[cf], acc[rf][cf], 0, 0, 0);
                acc[rf][cf] = __builtin_amdgcn_mfma_f32_16x16x32_bf16(ah[rf], bl[cf], acc[rf][cf], 0, 0, 0);
            }
        if (it < 15) {
            const int nxt = cur ^ 1;
            bf16x8 nAh, nAl;
            CVTHL(nAh, nAl, nv0, nv1)
            *(bf16x8*)&lds[nxt][0][ci] = nAh;
            *(bf16x8*)&lds[nxt][1][ci] = nAl;
            *(bf16x8*)&lds[nxt][2][ci] = nBh;
            *(bf16x8*)&lds[nxt][3][ci] = nBl;
            __syncthreads();
        }
    }
#undef CVTHL

    // epilogue: C/D layout col=lane&15, row=(lane>>4)*4+reg  [m89 verified]
    if (z == 2) {
#pragma unroll
        for (int rf = 0; rf < 2; rf++)
#pragma unroll
            for (int cf = 0; cf < 2; cf++) {
                int c = wc * 32 + cf * 16 + m;
                float bval = bias[colBase + c];
#pragma unroll
                for (int r = 0; r < 4; r++) {
                    int rr = rowBase + wr * 32 + rf * 16 + g * 4 + r;
                    int bb = rr >> 10, t = rr & (TT - 1);
                    Vv2[(((size_t)(bb * NH + h)) * TT + t) * HD + c] = (acc[rf][cf][r] + bval) * LOG2EF;
                }
            }
    } else {
        float beta = expf(lbeta[h]);
        float itemp = 1.0f / expf(ltemp[h]);
        float oscale = (z == 0) ? (LN2F / beta) : (1.0f / beta);
        float* __restrict__ dst = (z == 0) ? Qf2 : Kf;
#pragma unroll
        for (int rf = 0; rf < 2; rf++)
#pragma unroll
            for (int cf = 0; cf < 2; cf++) {
                int c = wc * 32 + cf * 16 + m;
                float bval = bias[colBase + c];
#pragma unroll
                for (int r = 0; r < 4; r++) {
                    int rr = rowBase + wr * 32 + rf * 16 + g * 4 + r;
                    int bb = rr >> 10, t = rr & (TT - 1);
                    float val = (acc[rf][cf][r] + bval) * itemp;
                    float zz = beta * val;
                    float sp = (fmaxf(zz, 0.f) + log1pf(expf(-fabsf(zz)))) * oscale;
                    dst[(((size_t)(bb * NH + h)) * TT + t) * HD + c] = sp;
                }
            }
    }
}

// ---------------- Kernel 2: per-chunk local sums (CL=16) ----------------
__launch_bounds__(256)
__global__ void k_chunk_reduce(const float* __restrict__ Kf, const float* __restrict__ Vv2,
                               float* __restrict__ aA, float* __restrict__ aD,
                               float* __restrict__ aCM)
{
    const int c = blockIdx.x >> 1, qh = blockIdx.x & 1;
    const int bh = blockIdx.z * NH + blockIdx.y;
    const int tid = threadIdx.x;

    __shared__ __align__(16) float sK[CL * HD];
    __shared__ __align__(16) float sV2[CL * HD];
    __shared__ __align__(16) float sM02[CL * HD];

    size_t base = ((size_t)bh * TT + (size_t)c * CL) * HD;
    const float4* K4 = (const float4*)(Kf + base);
    const float4* V4 = (const float4*)(Vv2 + base);
    {
        int f = tid;
        float4 kv = K4[f];
        ((float4*)sK)[f] = kv;
        float4 mm;
        mm.x = flog2(kv.x + EPSF); mm.y = flog2(kv.y + EPSF);
        mm.z = flog2(kv.z + EPSF); mm.w = flog2(kv.w + EPSF);
        ((float4*)sM02)[f] = mm;
        ((float4*)sV2)[f] = V4[f];
    }
    __syncthreads();

    const int p = tid & 63, qo = tid >> 6;
    const int q0 = qh * 32 + qo * 8;
    float A[8] = {};
    float AD = 0.f, cmx = 0.f;
    const bool doD = (qh == 0) && (tid < 64);

#pragma unroll
    for (int s = 0; s < CL; s++) {
        float vp = sV2[s * HD + p];
        float mp = sM02[s * HD + p];
        float4 ka = *(const float4*)&sK[s * HD + q0];
        float4 kb = *(const float4*)&sK[s * HD + q0 + 4];
        A[0] += fexp2(fmaf(vp, ka.x, mp));
        A[1] += fexp2(fmaf(vp, ka.y, mp));
        A[2] += fexp2(fmaf(vp, ka.z, mp));
        A[3] += fexp2(fmaf(vp, ka.w, mp));
        A[4] += fexp2(fmaf(vp, kb.x, mp));
        A[5] += fexp2(fmaf(vp, kb.y, mp));
        A[6] += fexp2(fmaf(vp, kb.z, mp));
        A[7] += fexp2(fmaf(vp, kb.w, mp));
        if (doD) {
            float kn = sK[s * HD + tid];
            float ke = kn + EPSF;
            AD += fexp2(kn * LOG2EF) * ke;
            cmx = fmaxf(cmx, ke);
        }
    }

    size_t abase = ((size_t)bh * CH + c) * 4096 + (size_t)p * HD + q0;
    float4 o0 = { A[0], A[1], A[2], A[3] };
    float4 o1 = { A[4], A[5], A[6], A[7] };
    *(float4*)&aA[abase] = o0;
    *(float4*)&aA[abase + 4] = o1;
    if (doD) {
        size_t dbase = ((size_t)bh * CH + c) * HD + tid;
        aD[dbase] = AD; aCM[dbase] = cmx;
    }
}

// ---------------- Kernel 3: exclusive scan of chunk aggregates (float4) -------
__global__ void k_scan_agg(float* __restrict__ aA, float* __restrict__ aD,
                           float* __restrict__ aCM, int BH)
{
    int idx = blockIdx.x * 256 + threadIdx.x;
    int nA4 = BH * 1024;          // BH*4096/4
    int nD4 = BH * 16;            // BH*64/4
    if (idx < nA4) {
        int bh = idx >> 10, pn4 = (idx & 1023) * 4;
        float4 Sr = {0.f, 0.f, 0.f, 0.f};
        for (int c = 0; c < CH; c++) {
            float* p = &aA[((size_t)bh * CH + c) * 4096 + pn4];
            float4 t = *(float4*)p;
            *(float4*)p = Sr;
            Sr.x += t.x; Sr.y += t.y; Sr.z += t.z; Sr.w += t.w;
        }
    } else if (idx < nA4 + nD4) {
        int i = idx - nA4; int bh = i >> 4, n4 = (i & 15) * 4;
        float4 Sr = {0.f, 0.f, 0.f, 0.f};
        for (int c = 0; c < CH; c++) {
            float* p = &aD[((size_t)bh * CH + c) * HD + n4];
            float4 t = *(float4*)p;
            *(float4*)p = Sr;
            Sr.x += t.x; Sr.y += t.y; Sr.z += t.z; Sr.w += t.w;
        }
    } else if (idx < nA4 + 2 * nD4) {
        int i = idx - nA4 - nD4; int bh = i >> 4, n4 = (i & 15) * 4;
        float4 r = {0.f, 0.f, 0.f, 0.f};
        for (int c = 0; c < CH; c++) {
            float* p = &aCM[((size_t)bh * CH + c) * HD + n4];
            float4 t = *(float4*)p;
            *(float4*)p = r;
            r.x = fmaxf(r.x, t.x); r.y = fmaxf(r.y, t.y);
            r.z = fmaxf(r.z, t.z); r.w = fmaxf(r.w, t.w);
        }
    }
}

// ---------------- Kernel 4: rescan + FUSED den + output Y (bf16, CL=16) -------
// round-13 proven version: 256 thr, 1 chunk/block, grid (CH,NH,B)=1024.
__launch_bounds__(256)
__global__ void k_chunk_out(const float* __restrict__ Kf, const float* __restrict__ Vv2,
                            const float* __restrict__ Qf2, const float* __restrict__ aA,
                            const float* __restrict__ aD, const float* __restrict__ aCM,
                            const float* __restrict__ lsharp, ushort_t* __restrict__ Ymb)
{
    const int c = blockIdx.x, hh = blockIdx.y, bb = blockIdx.z;
    const int bh = bb * NH + hh;
    const int tid = threadIdx.x;

    __shared__ __align__(16) float sK[CL * HD];
    __shared__ __align__(16) float sV2[CL * HD];
    __shared__ __align__(16) float sM02[CL * HD];
    __shared__ __align__(16) float sQ2[CL * HD];
    __shared__ float sC1[CL], sIV[CL];

    size_t base = ((size_t)bh * TT + (size_t)c * CL) * HD;
    const float4* K4 = (const float4*)(Kf + base);
    const float4* V4 = (const float4*)(Vv2 + base);
    const float4* Q4 = (const float4*)(Qf2 + base);
    {
        int f = tid;
        float4 kv = K4[f];
        ((float4*)sK)[f] = kv;
        float4 mm;
        mm.x = flog2(kv.x + EPSF); mm.y = flog2(kv.y + EPSF);
        mm.z = flog2(kv.z + EPSF); mm.w = flog2(kv.w + EPSF);
        ((float4*)sM02)[f] = mm;
        ((float4*)sV2)[f] = V4[f];
        ((float4*)sQ2)[f] = Q4[f];
    }
    __syncthreads();

    const int lane = tid & 63, w = tid >> 6;
    const int g = lane >> 3, qil = lane & 7;
    const int qA = w * 8 + qil, qB = qA + 32;
    const int p0 = g * 8;

    // A-state init (issue loads early)
    float A[8], Bq[8];
    size_t abase = ((size_t)bh * CH + c) * 4096;
#pragma unroll
    for (int j = 0; j < 8; j++) {
        A[j]  = aA[abase + (size_t)(p0 + j) * HD + qA];
        Bq[j] = aA[abase + (size_t)(p0 + j) * HD + qB];
    }

    // ---- fused den phase ----
    {
        size_t dofs = ((size_t)bh * CH + c) * HD + lane;
        float AD = aD[dofs], cmx = aCM[dofs];
#pragma unroll
        for (int s = 0; s < CL; s++) {
            float kn = sK[s * HD + lane];
            float ke = kn + EPSF;
            AD += fexp2(kn * LOG2EF) * ke;     // e^k * (k+eps)
            cmx = fmaxf(cmx, ke);
            if ((s & 3) == w) {
                float qn = sQ2[s * HD + lane];
                float t1 = qn * flog2(cmx);
                float t2 = qn * flog2(AD);
#pragma unroll
                for (int off = 1; off <= 32; off <<= 1) {
                    t1 += __shfl_xor(t1, off);
                    t2 += __shfl_xor(t2, off);
                }
                if (lane == 0) {
                    sC1[s] = t1;
                    sIV[s] = 1.0f / (t2 - t1 + EPSF);
                }
            }
        }
    }
    __syncthreads();

    const float sharp = expf(lsharp[hh]);
    const float invT = 1.0f / (float)TT;

#pragma unroll 4
    for (int s = 0; s < CL; s++) {
        float kqA = sK[s * HD + qA];
        float kqB = sK[s * HD + qB];
        float pA0 = 0.f, pA1 = 0.f, pB0 = 0.f, pB1 = 0.f;
#pragma unroll
        for (int j4 = 0; j4 < 2; j4++) {
            float4 vv = *(const float4*)&sV2[s * HD + p0 + j4 * 4];
            float4 mm = *(const float4*)&sM02[s * HD + p0 + j4 * 4];
            float4 qv = *(const float4*)&sQ2[s * HD + p0 + j4 * 4];
#define STEP(comp, jj, PA, PB) { \
            A[jj]  += fexp2(fmaf(vv.comp, kqA, mm.comp)); \
            PA = fmaf(qv.comp, flog2(A[jj]), PA); \
            Bq[jj] += fexp2(fmaf(vv.comp, kqB, mm.comp)); \
            PB = fmaf(qv.comp, flog2(Bq[jj]), PB); }
            STEP(x, j4 * 4 + 0, pA0, pB0)
            STEP(y, j4 * 4 + 1, pA1, pB1)
            STEP(z, j4 * 4 + 2, pA0, pB0)
            STEP(w, j4 * 4 + 3, pA1, pB1)
#undef STEP
        }
        float partA = pA0 + pA1;
        float partB = pB0 + pB1;
        partA += __shfl_xor(partA, 8);
        partA += __shfl_xor(partA, 16);
        partA += __shfl_xor(partA, 32);
        partB += __shfl_xor(partB, 8);
        partB += __shfl_xor(partB, 16);
        partB += __shfl_xor(partB, 32);

        float c1v = sC1[s], iv = sIV[s];
        int tg = c * CL + s;
        float scale = (float)(tg + 1) * invT;
        float yA = (partA - c1v) * iv;
        float yB = (partB - c1v) * iv;
        float oA = copysignf(fexp2(sharp * flog2(fabsf(yA))), yA) * scale;
        float oB = copysignf(fexp2(sharp * flog2(fabsf(yB))), yB) * scale;
        if (g == 0) {
            ushort_t* yrow = Ymb + ((size_t)(bb * TT + tg)) * DIM + hh * HD;
            yrow[qA] = f2bf(oA);
            yrow[qB] = f2bf(oB);
        }
    }
}

// ---------------- Kernel 5: output projection, LDS-staged MFMA (bf16) ---------
__launch_bounds__(256, 4)
__global__ void k_gemm_out(const ushort_t* __restrict__ Ymb, const ushort_t* __restrict__ wTo,
                           const float* __restrict__ bias, float* __restrict__ out)
{
    const int colBase = blockIdx.x * 64;
    const int rowBase = blockIdx.y * 32;

    __shared__ __align__(16) ushort_t sA[2][1024];
    __shared__ __align__(16) ushort_t sB[2][2048];

    const int tid = threadIdx.x;
    const int l = tid & 63, wv = tid >> 6;
    const int m = l & 15, g = l >> 4;
    const int wr = wv & 1, wc = wv >> 1;

    const int rlB = tid >> 2, ccB = tid & 3;
    const int ciB = ((rlB >> 4) * 64 + ccB * 16 + (rlB & 15)) * 8;
    const ushort_t* gB = wTo + (size_t)(colBase + rlB) * DIM + ccB * 8;
    const int rlA = (tid & 127) >> 2, ccA = tid & 3;
    const int ciA = ((rlA >> 4) * 64 + ccA * 16 + (rlA & 15)) * 8;
    const ushort_t* gA = Ymb + (size_t)(rowBase + rlA) * DIM + ccA * 8;
    const bool doA = tid < 128;

    f32x4 acc[2] = { {0,0,0,0}, {0,0,0,0} };

    {
        bf16x8 b0 = *(const bf16x8*)gB;
        *(bf16x8*)&sB[0][ciB] = b0;
        if (doA) {
            bf16x8 a0 = *(const bf16x8*)gA;
            *(bf16x8*)&sA[0][ciA] = a0;
        }
    }
    __syncthreads();

    for (int it = 0; it < 16; ++it) {
        const int cur = it & 1;
        bf16x8 nA, nB;
        if (it < 15) {
            const int K = (it + 1) * 32;
            nB = *(const bf16x8*)(gB + K);
            if (doA) nA = *(const bf16x8*)(gA + K);
        }
        bf16x8 a = *(const bf16x8*)&sA[cur][(wr * 64 + l) * 8];
#pragma unroll
        for (int n = 0; n < 2; n++) {
            bf16x8 b = *(const bf16x8*)&sB[cur][((wc * 2 + n) * 64 + l) * 8];
            acc[n] = __builtin_amdgcn_mfma_f32_16x16x32_bf16(a, b, acc[n], 0, 0, 0);
        }
        if (it < 15) {
            const int nxt = cur ^ 1;
            *(bf16x8*)&sB[nxt][ciB] = nB;
            if (doA) *(bf16x8*)&sA[nxt][ciA] = nA;
            __syncthreads();
        }
    }

#pragma unroll
    for (int n = 0; n < 2; n++) {
        int c = colBase + wc * 32 + n * 16 + m;
        float bval = bias[c];
#pragma unroll
        for (int r = 0; r < 4; r++) {
            int rr = rowBase + wr * 16 + g * 4 + r;
            out[(size_t)rr * DIM + c] = acc[n][r] + bval;
        }
    }
}

extern "C" void kernel_launch(void* const* d_in, const int* in_sizes, int n_in,
                              void* d_out, int out_size, void* d_ws, size_t ws_size,
                              hipStream_t stream)
{
    const float* x  = (const float*)d_in[0];
    const float* wq = (const float*)d_in[1];
    const float* bq = (const float*)d_in[2];
    const float* wk = (const float*)d_in[3];
    const float* bk = (const float*)d_in[4];
    const float* wv = (const float*)d_in[5];
    const float* bv = (const float*)d_in[6];
    const float* wo = (const float*)d_in[7];
    const float* bo = (const float*)d_in[8];
    const float* lb = (const float*)d_in[9];
    const float* lt = (const float*)d_in[10];
    const float* ls = (const float*)d_in[11];

    const int B  = in_sizes[0] / (TT * DIM);   // 2
    const int BH = B * NH;                     // 16

    float* ws = (float*)d_ws;
    const size_t nQ = (size_t)BH * TT * HD;      // 1,048,576 floats
    float* Qf2 = ws;
    float* Kf  = Qf2 + nQ;
    float* Vv2 = Kf + nQ;
    float* region = Vv2 + nQ;                    // phase-aliased region

    // phase 1-2 (cvt_w + qkv): weight staging at region start
    ushort_t* wTh = (ushort_t*)region;                                  // 3*DIM*DIM bf16
    ushort_t* wTl = wTh + (size_t)3 * DIM * DIM;
    // phase 3+ : scan state (wTh/wTl dead after qkv)
    ushort_t* Ymb = (ushort_t*)region;                                  // B*TT*DIM bf16
    float* aA  = region + (size_t)B * TT * DIM / 2;                     // after Ymb
    float* aD  = aA  + (size_t)BH * CH * 4096;
    float* aCM = aD  + (size_t)BH * CH * HD;
    ushort_t* wTo = (ushort_t*)(aCM + (size_t)BH * CH * HD);            // persists to end

    dim3 gw(DIM / 64, DIM / 128, 4);
    k_cvt_w<<<gw, 256, 0, stream>>>(wq, wk, wv, wo, wTh, wTl, wTo);

    dim3 g1(NH, (B * TT) / 64, 3);
    k_gemm_qkv<<<g1, 256, 0, stream>>>(x, wTh, wTl, bq, bk, bv, lb, lt, Qf2, Kf, Vv2);

    dim3 g2(CH * 2, NH, B);
    k_chunk_reduce<<<g2, 256, 0, stream>>>(Kf, Vv2, aA, aD, aCM);

    int ntot = BH * 1024 + 2 * BH * 16;
    k_scan_agg<<<(ntot + 255) / 256, 256, 0, stream>>>(aA, aD, aCM, BH);

    dim3 g4(CH, NH, B);
    k_chunk_out<<<g4, 256, 0, stream>>>(Kf, Vv2, Qf2, aA, aD, aCM, ls, Ymb);

    dim3 g6(DIM / 64, (B * TT) / 32);
    k_gemm_out<<<g6, 256, 0, stream>>>(Ymb, wTo, bo, (float*)d_out);
}

// Round 18
// 89.419 us; speedup vs baseline: 1.0780x; 1.0106x over previous
//
#include <hip/hip_runtime.h>
#include <hip/hip_bf16.h>
#include <math.h>

#define DIM 512
#define NH 8
#define HD 64
#define TT 1024
#define CH 64      // chunks per (b,h) sequence
#define CL 16      // chunk length (CH*CL == TT)
#define EPSF 1e-5f
#define LN2F 0.69314718056f
#define LOG2EF 1.44269504089f

typedef unsigned short ushort_t;
typedef __attribute__((ext_vector_type(8))) short bf16x8;
typedef __attribute__((ext_vector_type(4))) float f32x4;

// raw gfx950 hardware transcendentals: v_exp_f32 = 2^x, v_log_f32 = log2(x)
__device__ __forceinline__ float fexp2(float x) { return __builtin_amdgcn_exp2f(x); }
__device__ __forceinline__ float flog2(float x) { return __builtin_amdgcn_logf(x); }

__device__ __forceinline__ ushort_t f2bf(float f) {
    union { float f; unsigned u; } v; v.f = f;
    unsigned r = v.u + 0x7FFFu + ((v.u >> 16) & 1u);
    return (ushort_t)(r >> 16);
}
__device__ __forceinline__ float bf2f(ushort_t h) {
    union { unsigned u; float f; } v; v.u = ((unsigned)h) << 16;
    return v.f;
}

// ---------------- fused cvt: x -> bf16 hi/lo  AND  weights -> bf16 [n][k] -----
#define NXB 1024   // (B*TT*DIM)/1024 with B=2
__launch_bounds__(256)
__global__ void k_cvt(const float* __restrict__ x, ushort_t* __restrict__ xh,
                      ushort_t* __restrict__ xl,
                      const float* __restrict__ wq, const float* __restrict__ wk,
                      const float* __restrict__ wv, const float* __restrict__ wo,
                      ushort_t* __restrict__ wTh, ushort_t* __restrict__ wTl,
                      ushort_t* __restrict__ wTo)
{
    if (blockIdx.x < NXB) {
        int i = (blockIdx.x * 256 + threadIdx.x) * 4;
        float4 v = *(const float4*)&x[i];
        ushort4 h, l;
        h.x = f2bf(v.x); l.x = f2bf(v.x - bf2f(h.x));
        h.y = f2bf(v.y); l.y = f2bf(v.y - bf2f(h.y));
        h.z = f2bf(v.z); l.z = f2bf(v.z - bf2f(h.z));
        h.w = f2bf(v.w); l.w = f2bf(v.w - bf2f(h.w));
        *(ushort4*)&xh[i] = h;
        *(ushort4*)&xl[i] = l;
        return;
    }
    const int bid = blockIdx.x - NXB;
    const int mat = bid >> 5;
    const int rest = bid & 31;
    const int ky = rest >> 3, nx = rest & 7;
    const float* w = (mat == 0) ? wq : (mat == 1) ? wk : (mat == 2) ? wv : wo;
    const int n  = nx * 64 + (threadIdx.x & 63);
    const int k0 = ky * 128 + (threadIdx.x >> 6) * 32;

    ushort_t hb[32], lb[32];
#pragma unroll
    for (int j = 0; j < 32; j++) {
        float v = w[(size_t)(k0 + j) * DIM + n];
        hb[j] = f2bf(v);
        lb[j] = f2bf(v - bf2f(hb[j]));
    }
    if (mat < 3) {
        ushort_t* dh = wTh + (size_t)mat * DIM * DIM + (size_t)n * DIM + k0;
        ushort_t* dl = wTl + (size_t)mat * DIM * DIM + (size_t)n * DIM + k0;
#pragma unroll
        for (int j = 0; j < 8; j++) {
            ushort4 th = { hb[4*j], hb[4*j+1], hb[4*j+2], hb[4*j+3] };
            ushort4 tl = { lb[4*j], lb[4*j+1], lb[4*j+2], lb[4*j+3] };
            *(ushort4*)&dh[4*j] = th;
            *(ushort4*)&dl[4*j] = tl;
        }
    } else {
        ushort_t* dh = wTo + (size_t)n * DIM + k0;
#pragma unroll
        for (int j = 0; j < 8; j++) {
            ushort4 th = { hb[4*j], hb[4*j+1], hb[4*j+2], hb[4*j+3] };
            *(ushort4*)&dh[4*j] = th;
        }
    }
}

// ---------------- Kernel 1: QKV projection, LDS-staged MFMA (hi/lo bf16) -----
// 2x2 wave tiling: wave (wr,wc) computes 32 rows x 32 cols (2x2 16x16 frags).
__launch_bounds__(256, 4)
__global__ void k_gemm_qkv(const ushort_t* __restrict__ xh, const ushort_t* __restrict__ xl,
                           const ushort_t* __restrict__ wTh, const ushort_t* __restrict__ wTl,
                           const float* __restrict__ bq, const float* __restrict__ bk,
                           const float* __restrict__ bv,
                           const float* __restrict__ lbeta, const float* __restrict__ ltemp,
                           float* __restrict__ Qf2, float* __restrict__ Kf,
                           float* __restrict__ Vv2)
{
    const int z = blockIdx.z, h = blockIdx.x;
    const int rowBase = blockIdx.y * 64;
    const int colBase = h * 64;
    const float* bias = (z == 0) ? bq : (z == 1) ? bk : bv;

    __shared__ __align__(16) ushort_t lds[2][4][2048];

    const int tid = threadIdx.x;
    const int l = tid & 63, wv = tid >> 6;
    const int m = l & 15, g = l >> 4;
    const int wr = wv & 1, wc = wv >> 1;

    const int rl = tid >> 2, cc = tid & 3;
    const int ci = ((rl >> 4) * 64 + cc * 16 + (rl & 15)) * 8;
    const ushort_t* gAh = xh + (size_t)(rowBase + rl) * DIM + cc * 8;
    const ushort_t* gAl = xl + (size_t)(rowBase + rl) * DIM + cc * 8;
    const ushort_t* gBh = wTh + (size_t)z * DIM * DIM + (size_t)(colBase + rl) * DIM + cc * 8;
    const ushort_t* gBl = wTl + (size_t)z * DIM * DIM + (size_t)(colBase + rl) * DIM + cc * 8;

    f32x4 acc[2][2] = { { {0,0,0,0}, {0,0,0,0} }, { {0,0,0,0}, {0,0,0,0} } };

    {
        bf16x8 a0 = *(const bf16x8*)gAh;
        bf16x8 a1 = *(const bf16x8*)gAl;
        bf16x8 b0 = *(const bf16x8*)gBh;
        bf16x8 b1 = *(const bf16x8*)gBl;
        *(bf16x8*)&lds[0][0][ci] = a0;
        *(bf16x8*)&lds[0][1][ci] = a1;
        *(bf16x8*)&lds[0][2][ci] = b0;
        *(bf16x8*)&lds[0][3][ci] = b1;
    }
    __syncthreads();

    for (int it = 0; it < 16; ++it) {
        const int cur = it & 1;
        bf16x8 nAh, nAl, nBh, nBl;
        if (it < 15) {
            const int K = (it + 1) * 32;
            nAh = *(const bf16x8*)(gAh + K);
            nAl = *(const bf16x8*)(gAl + K);
            nBh = *(const bf16x8*)(gBh + K);
            nBl = *(const bf16x8*)(gBl + K);
        }
        bf16x8 ah[2], al[2], bh[2], bl[2];
#pragma unroll
        for (int rf = 0; rf < 2; rf++) {
            ah[rf] = *(const bf16x8*)&lds[cur][0][((wr * 2 + rf) * 64 + l) * 8];
            al[rf] = *(const bf16x8*)&lds[cur][1][((wr * 2 + rf) * 64 + l) * 8];
        }
#pragma unroll
        for (int cf = 0; cf < 2; cf++) {
            bh[cf] = *(const bf16x8*)&lds[cur][2][((wc * 2 + cf) * 64 + l) * 8];
            bl[cf] = *(const bf16x8*)&lds[cur][3][((wc * 2 + cf) * 64 + l) * 8];
        }
#pragma unroll
        for (int rf = 0; rf < 2; rf++)
#pragma unroll
            for (int cf = 0; cf < 2; cf++) {
                acc[rf][cf] = __builtin_amdgcn_mfma_f32_16x16x32_bf16(ah[rf], bh[cf], acc[rf][cf], 0, 0, 0);
                acc[rf][cf] = __builtin_amdgcn_mfma_f32_16x16x32_bf16(al[rf], bh[cf], acc[rf][cf], 0, 0, 0);
                acc[rf][cf] = __builtin_amdgcn_mfma_f32_16x16x32_bf16(ah[rf], bl[cf], acc[rf][cf], 0, 0, 0);
            }
        if (it < 15) {
            const int nxt = cur ^ 1;
            *(bf16x8*)&lds[nxt][0][ci] = nAh;
            *(bf16x8*)&lds[nxt][1][ci] = nAl;
            *(bf16x8*)&lds[nxt][2][ci] = nBh;
            *(bf16x8*)&lds[nxt][3][ci] = nBl;
            __syncthreads();
        }
    }

    // epilogue: C/D layout col=lane&15, row=(lane>>4)*4+reg  [m89 verified]
    if (z == 2) {
#pragma unroll
        for (int rf = 0; rf < 2; rf++)
#pragma unroll
            for (int cf = 0; cf < 2; cf++) {
                int c = wc * 32 + cf * 16 + m;
                float bval = bias[colBase + c];
#pragma unroll
                for (int r = 0; r < 4; r++) {
                    int rr = rowBase + wr * 32 + rf * 16 + g * 4 + r;
                    int bb = rr >> 10, t = rr & (TT - 1);
                    Vv2[(((size_t)(bb * NH + h)) * TT + t) * HD + c] = (acc[rf][cf][r] + bval) * LOG2EF;
                }
            }
    } else {
        float beta = expf(lbeta[h]);
        float itemp = 1.0f / expf(ltemp[h]);
        float oscale = (z == 0) ? (LN2F / beta) : (1.0f / beta);
        float* __restrict__ dst = (z == 0) ? Qf2 : Kf;
#pragma unroll
        for (int rf = 0; rf < 2; rf++)
#pragma unroll
            for (int cf = 0; cf < 2; cf++) {
                int c = wc * 32 + cf * 16 + m;
                float bval = bias[colBase + c];
#pragma unroll
                for (int r = 0; r < 4; r++) {
                    int rr = rowBase + wr * 32 + rf * 16 + g * 4 + r;
                    int bb = rr >> 10, t = rr & (TT - 1);
                    float val = (acc[rf][cf][r] + bval) * itemp;
                    float zz = beta * val;
                    float sp = (fmaxf(zz, 0.f) + log1pf(expf(-fabsf(zz)))) * oscale;
                    dst[(((size_t)(bb * NH + h)) * TT + t) * HD + c] = sp;
                }
            }
    }
}

// ---------------- Kernel 2: per-chunk local sums (CL=16) ----------------
__launch_bounds__(256)
__global__ void k_chunk_reduce(const float* __restrict__ Kf, const float* __restrict__ Vv2,
                               float* __restrict__ aA, float* __restrict__ aD,
                               float* __restrict__ aCM)
{
    const int c = blockIdx.x >> 1, qh = blockIdx.x & 1;
    const int bh = blockIdx.z * NH + blockIdx.y;
    const int tid = threadIdx.x;

    __shared__ __align__(16) float sK[CL * HD];
    __shared__ __align__(16) float sV2[CL * HD];
    __shared__ __align__(16) float sM02[CL * HD];

    size_t base = ((size_t)bh * TT + (size_t)c * CL) * HD;
    const float4* K4 = (const float4*)(Kf + base);
    const float4* V4 = (const float4*)(Vv2 + base);
    {
        int f = tid;
        float4 kv = K4[f];
        ((float4*)sK)[f] = kv;
        float4 mm;
        mm.x = flog2(kv.x + EPSF); mm.y = flog2(kv.y + EPSF);
        mm.z = flog2(kv.z + EPSF); mm.w = flog2(kv.w + EPSF);
        ((float4*)sM02)[f] = mm;
        ((float4*)sV2)[f] = V4[f];
    }
    __syncthreads();

    const int p = tid & 63, qo = tid >> 6;
    const int q0 = qh * 32 + qo * 8;
    float A[8] = {};
    float AD = 0.f, cmx = 0.f;
    const bool doD = (qh == 0) && (tid < 64);

#pragma unroll
    for (int s = 0; s < CL; s++) {
        float vp = sV2[s * HD + p];
        float mp = sM02[s * HD + p];
        float4 ka = *(const float4*)&sK[s * HD + q0];
        float4 kb = *(const float4*)&sK[s * HD + q0 + 4];
        A[0] += fexp2(fmaf(vp, ka.x, mp));
        A[1] += fexp2(fmaf(vp, ka.y, mp));
        A[2] += fexp2(fmaf(vp, ka.z, mp));
        A[3] += fexp2(fmaf(vp, ka.w, mp));
        A[4] += fexp2(fmaf(vp, kb.x, mp));
        A[5] += fexp2(fmaf(vp, kb.y, mp));
        A[6] += fexp2(fmaf(vp, kb.z, mp));
        A[7] += fexp2(fmaf(vp, kb.w, mp));
        if (doD) {
            float kn = sK[s * HD + tid];
            float ke = kn + EPSF;
            AD += fexp2(kn * LOG2EF) * ke;
            cmx = fmaxf(cmx, ke);
        }
    }

    size_t abase = ((size_t)bh * CH + c) * 4096 + (size_t)p * HD + q0;
    float4 o0 = { A[0], A[1], A[2], A[3] };
    float4 o1 = { A[4], A[5], A[6], A[7] };
    *(float4*)&aA[abase] = o0;
    *(float4*)&aA[abase + 4] = o1;
    if (doD) {
        size_t dbase = ((size_t)bh * CH + c) * HD + tid;
        aD[dbase] = AD; aCM[dbase] = cmx;
    }
}

// ---------------- Kernel 3: exclusive scan of chunk aggregates (float4) -------
__global__ void k_scan_agg(float* __restrict__ aA, float* __restrict__ aD,
                           float* __restrict__ aCM, int BH)
{
    int idx = blockIdx.x * 256 + threadIdx.x;
    int nA4 = BH * 1024;          // BH*4096/4
    int nD4 = BH * 16;            // BH*64/4
    if (idx < nA4) {
        int bh = idx >> 10, pn4 = (idx & 1023) * 4;
        float4 Sr = {0.f, 0.f, 0.f, 0.f};
        for (int c = 0; c < CH; c++) {
            float* p = &aA[((size_t)bh * CH + c) * 4096 + pn4];
            float4 t = *(float4*)p;
            *(float4*)p = Sr;
            Sr.x += t.x; Sr.y += t.y; Sr.z += t.z; Sr.w += t.w;
        }
    } else if (idx < nA4 + nD4) {
        int i = idx - nA4; int bh = i >> 4, n4 = (i & 15) * 4;
        float4 Sr = {0.f, 0.f, 0.f, 0.f};
        for (int c = 0; c < CH; c++) {
            float* p = &aD[((size_t)bh * CH + c) * HD + n4];
            float4 t = *(float4*)p;
            *(float4*)p = Sr;
            Sr.x += t.x; Sr.y += t.y; Sr.z += t.z; Sr.w += t.w;
        }
    } else if (idx < nA4 + 2 * nD4) {
        int i = idx - nA4 - nD4; int bh = i >> 4, n4 = (i & 15) * 4;
        float4 r = {0.f, 0.f, 0.f, 0.f};
        for (int c = 0; c < CH; c++) {
            float* p = &aCM[((size_t)bh * CH + c) * HD + n4];
            float4 t = *(float4*)p;
            *(float4*)p = r;
            r.x = fmaxf(r.x, t.x); r.y = fmaxf(r.y, t.y);
            r.z = fmaxf(r.z, t.z); r.w = fmaxf(r.w, t.w);
        }
    }
}

// ---------------- Kernel 4: rescan + FUSED den + output Y (bf16, CL=16) -------
// round-13 proven version: 256 thr, 1 chunk/block, grid (CH,NH,B)=1024.
__launch_bounds__(256)
__global__ void k_chunk_out(const float* __restrict__ Kf, const float* __restrict__ Vv2,
                            const float* __restrict__ Qf2, const float* __restrict__ aA,
                            const float* __restrict__ aD, const float* __restrict__ aCM,
                            const float* __restrict__ lsharp, ushort_t* __restrict__ Ymb)
{
    const int c = blockIdx.x, hh = blockIdx.y, bb = blockIdx.z;
    const int bh = bb * NH + hh;
    const int tid = threadIdx.x;

    __shared__ __align__(16) float sK[CL * HD];
    __shared__ __align__(16) float sV2[CL * HD];
    __shared__ __align__(16) float sM02[CL * HD];
    __shared__ __align__(16) float sQ2[CL * HD];
    __shared__ float sC1[CL], sIV[CL];

    size_t base = ((size_t)bh * TT + (size_t)c * CL) * HD;
    const float4* K4 = (const float4*)(Kf + base);
    const float4* V4 = (const float4*)(Vv2 + base);
    const float4* Q4 = (const float4*)(Qf2 + base);
    {
        int f = tid;
        float4 kv = K4[f];
        ((float4*)sK)[f] = kv;
        float4 mm;
        mm.x = flog2(kv.x + EPSF); mm.y = flog2(kv.y + EPSF);
        mm.z = flog2(kv.z + EPSF); mm.w = flog2(kv.w + EPSF);
        ((float4*)sM02)[f] = mm;
        ((float4*)sV2)[f] = V4[f];
        ((float4*)sQ2)[f] = Q4[f];
    }
    __syncthreads();

    const int lane = tid & 63, w = tid >> 6;
    const int g = lane >> 3, qil = lane & 7;
    const int qA = w * 8 + qil, qB = qA + 32;
    const int p0 = g * 8;

    // A-state init (issue loads early)
    float A[8], Bq[8];
    size_t abase = ((size_t)bh * CH + c) * 4096;
#pragma unroll
    for (int j = 0; j < 8; j++) {
        A[j]  = aA[abase + (size_t)(p0 + j) * HD + qA];
        Bq[j] = aA[abase + (size_t)(p0 + j) * HD + qB];
    }

    // ---- fused den phase ----
    {
        size_t dofs = ((size_t)bh * CH + c) * HD + lane;
        float AD = aD[dofs], cmx = aCM[dofs];
#pragma unroll
        for (int s = 0; s < CL; s++) {
            float kn = sK[s * HD + lane];
            float ke = kn + EPSF;
            AD += fexp2(kn * LOG2EF) * ke;     // e^k * (k+eps)
            cmx = fmaxf(cmx, ke);
            if ((s & 3) == w) {
                float qn = sQ2[s * HD + lane];
                float t1 = qn * flog2(cmx);
                float t2 = qn * flog2(AD);
#pragma unroll
                for (int off = 1; off <= 32; off <<= 1) {
                    t1 += __shfl_xor(t1, off);
                    t2 += __shfl_xor(t2, off);
                }
                if (lane == 0) {
                    sC1[s] = t1;
                    sIV[s] = 1.0f / (t2 - t1 + EPSF);
                }
            }
        }
    }
    __syncthreads();

    const float sharp = expf(lsharp[hh]);
    const float invT = 1.0f / (float)TT;

#pragma unroll 4
    for (int s = 0; s < CL; s++) {
        float kqA = sK[s * HD + qA];
        float kqB = sK[s * HD + qB];
        float pA0 = 0.f, pA1 = 0.f, pB0 = 0.f, pB1 = 0.f;
#pragma unroll
        for (int j4 = 0; j4 < 2; j4++) {
            float4 vv = *(const float4*)&sV2[s * HD + p0 + j4 * 4];
            float4 mm = *(const float4*)&sM02[s * HD + p0 + j4 * 4];
            float4 qv = *(const float4*)&sQ2[s * HD + p0 + j4 * 4];
#define STEP(comp, jj, PA, PB) { \
            A[jj]  += fexp2(fmaf(vv.comp, kqA, mm.comp)); \
            PA = fmaf(qv.comp, flog2(A[jj]), PA); \
            Bq[jj] += fexp2(fmaf(vv.comp, kqB, mm.comp)); \
            PB = fmaf(qv.comp, flog2(Bq[jj]), PB); }
            STEP(x, j4 * 4 + 0, pA0, pB0)
            STEP(y, j4 * 4 + 1, pA1, pB1)
            STEP(z, j4 * 4 + 2, pA0, pB0)
            STEP(w, j4 * 4 + 3, pA1, pB1)
#undef STEP
        }
        float partA = pA0 + pA1;
        float partB = pB0 + pB1;
        partA += __shfl_xor(partA, 8);
        partA += __shfl_xor(partA, 16);
        partA += __shfl_xor(partA, 32);
        partB += __shfl_xor(partB, 8);
        partB += __shfl_xor(partB, 16);
        partB += __shfl_xor(partB, 32);

        float c1v = sC1[s], iv = sIV[s];
        int tg = c * CL + s;
        float scale = (float)(tg + 1) * invT;
        float yA = (partA - c1v) * iv;
        float yB = (partB - c1v) * iv;
        float oA = copysignf(fexp2(sharp * flog2(fabsf(yA))), yA) * scale;
        float oB = copysignf(fexp2(sharp * flog2(fabsf(yB))), yB) * scale;
        if (g == 0) {
            ushort_t* yrow = Ymb + ((size_t)(bb * TT + tg)) * DIM + hh * HD;
            yrow[qA] = f2bf(oA);
            yrow[qB] = f2bf(oB);
        }
    }
}

// ---------------- Kernel 5: output projection, LDS-staged MFMA (bf16) ---------
// 32x32 tile, 4 waves (2x2 wave grid), grid (16,64)=1024 -> 4 blocks/CU,
// 16 waves/CU (2x round-13's gemm_out). 1 MFMA + 2 ds_read_b128 per wave-step.
__launch_bounds__(256)
__global__ void k_gemm_out(const ushort_t* __restrict__ Ymb, const ushort_t* __restrict__ wTo,
                           const float* __restrict__ bias, float* __restrict__ out)
{
    const int colBase = blockIdx.x * 32;
    const int rowBase = blockIdx.y * 32;

    __shared__ __align__(16) ushort_t sA[2][1024];   // 32 rows x 32 k
    __shared__ __align__(16) ushort_t sB[2][1024];   // 32 cols x 32 k

    const int tid = threadIdx.x;
    const int l = tid & 63, wv = tid >> 6;
    const int m = l & 15, g = l >> 4;
    const int wr = wv & 1, wc = wv >> 1;

    // staging: tid<128 stages A (32 rows x 4 kchunks), tid>=128 stages B.
    const int st = tid & 127;
    const int rl = st >> 2, cc = st & 3;
    const int ci = ((rl >> 4) * 64 + cc * 16 + (rl & 15)) * 8;
    const bool isA = tid < 128;
    const ushort_t* gp = isA ? (Ymb + (size_t)(rowBase + rl) * DIM + cc * 8)
                             : (wTo + (size_t)(colBase + rl) * DIM + cc * 8);
    ushort_t* sd0 = isA ? &sA[0][ci] : &sB[0][ci];
    ushort_t* sd1 = isA ? &sA[1][ci] : &sB[1][ci];

    f32x4 acc = {0, 0, 0, 0};

    {
        bf16x8 v = *(const bf16x8*)gp;
        *(bf16x8*)sd0 = v;
    }
    __syncthreads();

    for (int it = 0; it < 16; ++it) {
        const int cur = it & 1;
        bf16x8 nv;
        if (it < 15) nv = *(const bf16x8*)(gp + (it + 1) * 32);
        bf16x8 a = *(const bf16x8*)&sA[cur][(wr * 64 + l) * 8];
        bf16x8 b = *(const bf16x8*)&sB[cur][(wc * 64 + l) * 8];
        acc = __builtin_amdgcn_mfma_f32_16x16x32_bf16(a, b, acc, 0, 0, 0);
        if (it < 15) {
            ushort_t* sd = (cur ^ 1) ? sd1 : sd0;
            *(bf16x8*)sd = nv;
            __syncthreads();
        }
    }

    int c = colBase + wc * 16 + m;
    float bval = bias[c];
#pragma unroll
    for (int r = 0; r < 4; r++) {
        int rr = rowBase + wr * 16 + g * 4 + r;
        out[(size_t)rr * DIM + c] = acc[r] + bval;
    }
}

extern "C" void kernel_launch(void* const* d_in, const int* in_sizes, int n_in,
                              void* d_out, int out_size, void* d_ws, size_t ws_size,
                              hipStream_t stream)
{
    const float* x  = (const float*)d_in[0];
    const float* wq = (const float*)d_in[1];
    const float* bq = (const float*)d_in[2];
    const float* wk = (const float*)d_in[3];
    const float* bk = (const float*)d_in[4];
    const float* wv = (const float*)d_in[5];
    const float* bv = (const float*)d_in[6];
    const float* wo = (const float*)d_in[7];
    const float* bo = (const float*)d_in[8];
    const float* lb = (const float*)d_in[9];
    const float* lt = (const float*)d_in[10];
    const float* ls = (const float*)d_in[11];

    const int B  = in_sizes[0] / (TT * DIM);   // 2
    const int BH = B * NH;                     // 16

    float* ws = (float*)d_ws;
    const size_t nQ = (size_t)BH * TT * HD;      // 1,048,576 floats
    float* Qf2 = ws;
    float* Kf  = Qf2 + nQ;
    float* Vv2 = Kf + nQ;
    float* region = Vv2 + nQ;                    // phase-aliased region

    // phase 1-2 (cvt + qkv): bf16 staging lives in region
    ushort_t* xh  = (ushort_t*)region;                                  // B*TT*DIM bf16
    ushort_t* xl  = xh + (size_t)B * TT * DIM;
    ushort_t* wTh = (ushort_t*)(region + (size_t)B * TT * DIM);         // 3*DIM*DIM bf16
    ushort_t* wTl = wTh + (size_t)3 * DIM * DIM;
    // phase 3+ : scan state overwrites the staging area
    ushort_t* Ymb = (ushort_t*)region;                                  // B*TT*DIM bf16
    float* aA  = region + (size_t)B * TT * DIM;                         // BH*CH*4096
    float* aD  = aA  + (size_t)BH * CH * 4096;
    float* aCM = aD  + (size_t)BH * CH * HD;
    ushort_t* wTo = (ushort_t*)(aCM + (size_t)BH * CH * HD);            // persists to end

    k_cvt<<<NXB + 128, 256, 0, stream>>>(x, xh, xl, wq, wk, wv, wo, wTh, wTl, wTo);

    dim3 g1(NH, (B * TT) / 64, 3);
    k_gemm_qkv<<<g1, 256, 0, stream>>>(xh, xl, wTh, wTl, bq, bk, bv, lb, lt, Qf2, Kf, Vv2);

    dim3 g2(CH * 2, NH, B);
    k_chunk_reduce<<<g2, 256, 0, stream>>>(Kf, Vv2, aA, aD, aCM);

    int ntot = BH * 1024 + 2 * BH * 16;
    k_scan_agg<<<(ntot + 255) / 256, 256, 0, stream>>>(aA, aD, aCM, BH);

    dim3 g4(CH, NH, B);
    k_chunk_out<<<g4, 256, 0, stream>>>(Kf, Vv2, Qf2, aA, aD, aCM, ls, Ymb);

    dim3 g6(DIM / 32, (B * TT) / 32);
    k_gemm_out<<<g6, 256, 0, stream>>>(Ymb, wTo, bo, (float*)d_out);
}

// Round 19
// 86.402 us; speedup vs baseline: 1.1156x; 1.0349x over previous
//
#include <hip/hip_runtime.h>
#include <hip/hip_bf16.h>
#include <math.h>

#define DIM 512
#define NH 8
#define HD 64
#define TT 1024
#define CH 64      // chunks per (b,h) sequence
#define CL 16      // chunk length (CH*CL == TT)
#define EPSF 1e-5f
#define LN2F 0.69314718056f
#define LOG2EF 1.44269504089f

typedef unsigned short ushort_t;
typedef __attribute__((ext_vector_type(8))) short bf16x8;
typedef __attribute__((ext_vector_type(4))) float f32x4;

// raw gfx950 hardware transcendentals: v_exp_f32 = 2^x, v_log_f32 = log2(x)
__device__ __forceinline__ float fexp2(float x) { return __builtin_amdgcn_exp2f(x); }
__device__ __forceinline__ float flog2(float x) { return __builtin_amdgcn_logf(x); }

__device__ __forceinline__ ushort_t f2bf(float f) {
    union { float f; unsigned u; } v; v.f = f;
    unsigned r = v.u + 0x7FFFu + ((v.u >> 16) & 1u);
    return (ushort_t)(r >> 16);
}
__device__ __forceinline__ float bf2f(ushort_t h) {
    union { unsigned u; float f; } v; v.u = ((unsigned)h) << 16;
    return v.f;
}

// ---------------- fused cvt: x -> bf16 hi/lo  AND  weights -> bf16 [n][k] -----
#define NXB 1024   // (B*TT*DIM)/1024 with B=2
__launch_bounds__(256)
__global__ void k_cvt(const float* __restrict__ x, ushort_t* __restrict__ xh,
                      ushort_t* __restrict__ xl,
                      const float* __restrict__ wq, const float* __restrict__ wk,
                      const float* __restrict__ wv, const float* __restrict__ wo,
                      ushort_t* __restrict__ wTh, ushort_t* __restrict__ wTl,
                      ushort_t* __restrict__ wTo)
{
    if (blockIdx.x < NXB) {
        int i = (blockIdx.x * 256 + threadIdx.x) * 4;
        float4 v = *(const float4*)&x[i];
        ushort4 h, l;
        h.x = f2bf(v.x); l.x = f2bf(v.x - bf2f(h.x));
        h.y = f2bf(v.y); l.y = f2bf(v.y - bf2f(h.y));
        h.z = f2bf(v.z); l.z = f2bf(v.z - bf2f(h.z));
        h.w = f2bf(v.w); l.w = f2bf(v.w - bf2f(h.w));
        *(ushort4*)&xh[i] = h;
        *(ushort4*)&xl[i] = l;
        return;
    }
    const int bid = blockIdx.x - NXB;
    const int mat = bid >> 5;
    const int rest = bid & 31;
    const int ky = rest >> 3, nx = rest & 7;
    const float* w = (mat == 0) ? wq : (mat == 1) ? wk : (mat == 2) ? wv : wo;
    const int n  = nx * 64 + (threadIdx.x & 63);
    const int k0 = ky * 128 + (threadIdx.x >> 6) * 32;

    ushort_t hb[32], lb[32];
#pragma unroll
    for (int j = 0; j < 32; j++) {
        float v = w[(size_t)(k0 + j) * DIM + n];
        hb[j] = f2bf(v);
        lb[j] = f2bf(v - bf2f(hb[j]));
    }
    if (mat < 3) {
        ushort_t* dh = wTh + (size_t)mat * DIM * DIM + (size_t)n * DIM + k0;
        ushort_t* dl = wTl + (size_t)mat * DIM * DIM + (size_t)n * DIM + k0;
#pragma unroll
        for (int j = 0; j < 8; j++) {
            ushort4 th = { hb[4*j], hb[4*j+1], hb[4*j+2], hb[4*j+3] };
            ushort4 tl = { lb[4*j], lb[4*j+1], lb[4*j+2], lb[4*j+3] };
            *(ushort4*)&dh[4*j] = th;
            *(ushort4*)&dl[4*j] = tl;
        }
    } else {
        ushort_t* dh = wTo + (size_t)n * DIM + k0;
#pragma unroll
        for (int j = 0; j < 8; j++) {
            ushort4 th = { hb[4*j], hb[4*j+1], hb[4*j+2], hb[4*j+3] };
            *(ushort4*)&dh[4*j] = th;
        }
    }
}

// ---------------- Kernel 1: QKV projection, LDS-staged MFMA (hi/lo bf16) -----
// 2x2 wave tiling: wave (wr,wc) computes 32 rows x 32 cols (2x2 16x16 frags).
__launch_bounds__(256, 4)
__global__ void k_gemm_qkv(const ushort_t* __restrict__ xh, const ushort_t* __restrict__ xl,
                           const ushort_t* __restrict__ wTh, const ushort_t* __restrict__ wTl,
                           const float* __restrict__ bq, const float* __restrict__ bk,
                           const float* __restrict__ bv,
                           const float* __restrict__ lbeta, const float* __restrict__ ltemp,
                           float* __restrict__ Qf2, float* __restrict__ Kf,
                           float* __restrict__ Vv2)
{
    const int z = blockIdx.z, h = blockIdx.x;
    const int rowBase = blockIdx.y * 64;
    const int colBase = h * 64;
    const float* bias = (z == 0) ? bq : (z == 1) ? bk : bv;

    __shared__ __align__(16) ushort_t lds[2][4][2048];

    const int tid = threadIdx.x;
    const int l = tid & 63, wv = tid >> 6;
    const int m = l & 15, g = l >> 4;
    const int wr = wv & 1, wc = wv >> 1;

    const int rl = tid >> 2, cc = tid & 3;
    const int ci = ((rl >> 4) * 64 + cc * 16 + (rl & 15)) * 8;
    const ushort_t* gAh = xh + (size_t)(rowBase + rl) * DIM + cc * 8;
    const ushort_t* gAl = xl + (size_t)(rowBase + rl) * DIM + cc * 8;
    const ushort_t* gBh = wTh + (size_t)z * DIM * DIM + (size_t)(colBase + rl) * DIM + cc * 8;
    const ushort_t* gBl = wTl + (size_t)z * DIM * DIM + (size_t)(colBase + rl) * DIM + cc * 8;

    f32x4 acc[2][2] = { { {0,0,0,0}, {0,0,0,0} }, { {0,0,0,0}, {0,0,0,0} } };

    {
        bf16x8 a0 = *(const bf16x8*)gAh;
        bf16x8 a1 = *(const bf16x8*)gAl;
        bf16x8 b0 = *(const bf16x8*)gBh;
        bf16x8 b1 = *(const bf16x8*)gBl;
        *(bf16x8*)&lds[0][0][ci] = a0;
        *(bf16x8*)&lds[0][1][ci] = a1;
        *(bf16x8*)&lds[0][2][ci] = b0;
        *(bf16x8*)&lds[0][3][ci] = b1;
    }
    __syncthreads();

    for (int it = 0; it < 16; ++it) {
        const int cur = it & 1;
        bf16x8 nAh, nAl, nBh, nBl;
        if (it < 15) {
            const int K = (it + 1) * 32;
            nAh = *(const bf16x8*)(gAh + K);
            nAl = *(const bf16x8*)(gAl + K);
            nBh = *(const bf16x8*)(gBh + K);
            nBl = *(const bf16x8*)(gBl + K);
        }
        bf16x8 ah[2], al[2], bh[2], bl[2];
#pragma unroll
        for (int rf = 0; rf < 2; rf++) {
            ah[rf] = *(const bf16x8*)&lds[cur][0][((wr * 2 + rf) * 64 + l) * 8];
            al[rf] = *(const bf16x8*)&lds[cur][1][((wr * 2 + rf) * 64 + l) * 8];
        }
#pragma unroll
        for (int cf = 0; cf < 2; cf++) {
            bh[cf] = *(const bf16x8*)&lds[cur][2][((wc * 2 + cf) * 64 + l) * 8];
            bl[cf] = *(const bf16x8*)&lds[cur][3][((wc * 2 + cf) * 64 + l) * 8];
        }
#pragma unroll
        for (int rf = 0; rf < 2; rf++)
#pragma unroll
            for (int cf = 0; cf < 2; cf++) {
                acc[rf][cf] = __builtin_amdgcn_mfma_f32_16x16x32_bf16(ah[rf], bh[cf], acc[rf][cf], 0, 0, 0);
                acc[rf][cf] = __builtin_amdgcn_mfma_f32_16x16x32_bf16(al[rf], bh[cf], acc[rf][cf], 0, 0, 0);
                acc[rf][cf] = __builtin_amdgcn_mfma_f32_16x16x32_bf16(ah[rf], bl[cf], acc[rf][cf], 0, 0, 0);
            }
        if (it < 15) {
            const int nxt = cur ^ 1;
            *(bf16x8*)&lds[nxt][0][ci] = nAh;
            *(bf16x8*)&lds[nxt][1][ci] = nAl;
            *(bf16x8*)&lds[nxt][2][ci] = nBh;
            *(bf16x8*)&lds[nxt][3][ci] = nBl;
            __syncthreads();
        }
    }

    // epilogue: C/D layout col=lane&15, row=(lane>>4)*4+reg  [m89 verified]
    if (z == 2) {
#pragma unroll
        for (int rf = 0; rf < 2; rf++)
#pragma unroll
            for (int cf = 0; cf < 2; cf++) {
                int c = wc * 32 + cf * 16 + m;
                float bval = bias[colBase + c];
#pragma unroll
                for (int r = 0; r < 4; r++) {
                    int rr = rowBase + wr * 32 + rf * 16 + g * 4 + r;
                    int bb = rr >> 10, t = rr & (TT - 1);
                    Vv2[(((size_t)(bb * NH + h)) * TT + t) * HD + c] = (acc[rf][cf][r] + bval) * LOG2EF;
                }
            }
    } else {
        float beta = expf(lbeta[h]);
        float itemp = 1.0f / expf(ltemp[h]);
        float oscale = (z == 0) ? (LN2F / beta) : (1.0f / beta);
        float* __restrict__ dst = (z == 0) ? Qf2 : Kf;
#pragma unroll
        for (int rf = 0; rf < 2; rf++)
#pragma unroll
            for (int cf = 0; cf < 2; cf++) {
                int c = wc * 32 + cf * 16 + m;
                float bval = bias[colBase + c];
#pragma unroll
                for (int r = 0; r < 4; r++) {
                    int rr = rowBase + wr * 32 + rf * 16 + g * 4 + r;
                    int bb = rr >> 10, t = rr & (TT - 1);
                    float val = (acc[rf][cf][r] + bval) * itemp;
                    float zz = beta * val;
                    // stable softplus via hw trans: ln(1+e^-|z|) = ln2*log2(1+2^(-|z|*log2e))
                    float e = fexp2(-fabsf(zz) * LOG2EF);
                    float sp = (fmaxf(zz, 0.f) + LN2F * flog2(1.0f + e)) * oscale;
                    dst[(((size_t)(bb * NH + h)) * TT + t) * HD + c] = sp;
                }
            }
    }
}

// ---------------- Kernel 2: per-chunk local sums (CL=16) ----------------
__launch_bounds__(256)
__global__ void k_chunk_reduce(const float* __restrict__ Kf, const float* __restrict__ Vv2,
                               float* __restrict__ aA, float* __restrict__ aD,
                               float* __restrict__ aCM)
{
    const int c = blockIdx.x >> 1, qh = blockIdx.x & 1;
    const int bh = blockIdx.z * NH + blockIdx.y;
    const int tid = threadIdx.x;

    __shared__ __align__(16) float sK[CL * HD];
    __shared__ __align__(16) float sV2[CL * HD];
    __shared__ __align__(16) float sM02[CL * HD];

    size_t base = ((size_t)bh * TT + (size_t)c * CL) * HD;
    const float4* K4 = (const float4*)(Kf + base);
    const float4* V4 = (const float4*)(Vv2 + base);
    {
        int f = tid;
        float4 kv = K4[f];
        ((float4*)sK)[f] = kv;
        float4 mm;
        mm.x = flog2(kv.x + EPSF); mm.y = flog2(kv.y + EPSF);
        mm.z = flog2(kv.z + EPSF); mm.w = flog2(kv.w + EPSF);
        ((float4*)sM02)[f] = mm;
        ((float4*)sV2)[f] = V4[f];
    }
    __syncthreads();

    const int p = tid & 63, qo = tid >> 6;
    const int q0 = qh * 32 + qo * 8;
    float A[8] = {};
    float AD = 0.f, cmx = 0.f;
    const bool doD = (qh == 0) && (tid < 64);

#pragma unroll
    for (int s = 0; s < CL; s++) {
        float vp = sV2[s * HD + p];
        float mp = sM02[s * HD + p];
        float4 ka = *(const float4*)&sK[s * HD + q0];
        float4 kb = *(const float4*)&sK[s * HD + q0 + 4];
        A[0] += fexp2(fmaf(vp, ka.x, mp));
        A[1] += fexp2(fmaf(vp, ka.y, mp));
        A[2] += fexp2(fmaf(vp, ka.z, mp));
        A[3] += fexp2(fmaf(vp, ka.w, mp));
        A[4] += fexp2(fmaf(vp, kb.x, mp));
        A[5] += fexp2(fmaf(vp, kb.y, mp));
        A[6] += fexp2(fmaf(vp, kb.z, mp));
        A[7] += fexp2(fmaf(vp, kb.w, mp));
        if (doD) {
            float kn = sK[s * HD + tid];
            float ke = kn + EPSF;
            AD += fexp2(kn * LOG2EF) * ke;
            cmx = fmaxf(cmx, ke);
        }
    }

    size_t abase = ((size_t)bh * CH + c) * 4096 + (size_t)p * HD + q0;
    float4 o0 = { A[0], A[1], A[2], A[3] };
    float4 o1 = { A[4], A[5], A[6], A[7] };
    *(float4*)&aA[abase] = o0;
    *(float4*)&aA[abase + 4] = o1;
    if (doD) {
        size_t dbase = ((size_t)bh * CH + c) * HD + tid;
        aD[dbase] = AD; aCM[dbase] = cmx;
    }
}

// ---------------- Kernel 3: exclusive scan of chunk aggregates (float4) -------
__global__ void k_scan_agg(float* __restrict__ aA, float* __restrict__ aD,
                           float* __restrict__ aCM, int BH)
{
    int idx = blockIdx.x * 256 + threadIdx.x;
    int nA4 = BH * 1024;          // BH*4096/4
    int nD4 = BH * 16;            // BH*64/4
    if (idx < nA4) {
        int bh = idx >> 10, pn4 = (idx & 1023) * 4;
        float4 Sr = {0.f, 0.f, 0.f, 0.f};
        for (int c = 0; c < CH; c++) {
            float* p = &aA[((size_t)bh * CH + c) * 4096 + pn4];
            float4 t = *(float4*)p;
            *(float4*)p = Sr;
            Sr.x += t.x; Sr.y += t.y; Sr.z += t.z; Sr.w += t.w;
        }
    } else if (idx < nA4 + nD4) {
        int i = idx - nA4; int bh = i >> 4, n4 = (i & 15) * 4;
        float4 Sr = {0.f, 0.f, 0.f, 0.f};
        for (int c = 0; c < CH; c++) {
            float* p = &aD[((size_t)bh * CH + c) * HD + n4];
            float4 t = *(float4*)p;
            *(float4*)p = Sr;
            Sr.x += t.x; Sr.y += t.y; Sr.z += t.z; Sr.w += t.w;
        }
    } else if (idx < nA4 + 2 * nD4) {
        int i = idx - nA4 - nD4; int bh = i >> 4, n4 = (i & 15) * 4;
        float4 r = {0.f, 0.f, 0.f, 0.f};
        for (int c = 0; c < CH; c++) {
            float* p = &aCM[((size_t)bh * CH + c) * HD + n4];
            float4 t = *(float4*)p;
            *(float4*)p = r;
            r.x = fmaxf(r.x, t.x); r.y = fmaxf(r.y, t.y);
            r.z = fmaxf(r.z, t.z); r.w = fmaxf(r.w, t.w);
        }
    }
}

// ---------------- Kernel 4: rescan + FUSED den + output Y (bf16, CL=16) -------
// round-13 proven version: 256 thr, 1 chunk/block, grid (CH,NH,B)=1024.
__launch_bounds__(256)
__global__ void k_chunk_out(const float* __restrict__ Kf, const float* __restrict__ Vv2,
                            const float* __restrict__ Qf2, const float* __restrict__ aA,
                            const float* __restrict__ aD, const float* __restrict__ aCM,
                            const float* __restrict__ lsharp, ushort_t* __restrict__ Ymb)
{
    const int c = blockIdx.x, hh = blockIdx.y, bb = blockIdx.z;
    const int bh = bb * NH + hh;
    const int tid = threadIdx.x;

    __shared__ __align__(16) float sK[CL * HD];
    __shared__ __align__(16) float sV2[CL * HD];
    __shared__ __align__(16) float sM02[CL * HD];
    __shared__ __align__(16) float sQ2[CL * HD];
    __shared__ float sC1[CL], sIV[CL];

    size_t base = ((size_t)bh * TT + (size_t)c * CL) * HD;
    const float4* K4 = (const float4*)(Kf + base);
    const float4* V4 = (const float4*)(Vv2 + base);
    const float4* Q4 = (const float4*)(Qf2 + base);
    {
        int f = tid;
        float4 kv = K4[f];
        ((float4*)sK)[f] = kv;
        float4 mm;
        mm.x = flog2(kv.x + EPSF); mm.y = flog2(kv.y + EPSF);
        mm.z = flog2(kv.z + EPSF); mm.w = flog2(kv.w + EPSF);
        ((float4*)sM02)[f] = mm;
        ((float4*)sV2)[f] = V4[f];
        ((float4*)sQ2)[f] = Q4[f];
    }
    __syncthreads();

    const int lane = tid & 63, w = tid >> 6;
    const int g = lane >> 3, qil = lane & 7;
    const int qA = w * 8 + qil, qB = qA + 32;
    const int p0 = g * 8;

    // A-state init (issue loads early)
    float A[8], Bq[8];
    size_t abase = ((size_t)bh * CH + c) * 4096;
#pragma unroll
    for (int j = 0; j < 8; j++) {
        A[j]  = aA[abase + (size_t)(p0 + j) * HD + qA];
        Bq[j] = aA[abase + (size_t)(p0 + j) * HD + qB];
    }

    // ---- fused den phase ----
    {
        size_t dofs = ((size_t)bh * CH + c) * HD + lane;
        float AD = aD[dofs], cmx = aCM[dofs];
#pragma unroll
        for (int s = 0; s < CL; s++) {
            float kn = sK[s * HD + lane];
            float ke = kn + EPSF;
            AD += fexp2(kn * LOG2EF) * ke;     // e^k * (k+eps)
            cmx = fmaxf(cmx, ke);
            if ((s & 3) == w) {
                float qn = sQ2[s * HD + lane];
                float t1 = qn * flog2(cmx);
                float t2 = qn * flog2(AD);
#pragma unroll
                for (int off = 1; off <= 32; off <<= 1) {
                    t1 += __shfl_xor(t1, off);
                    t2 += __shfl_xor(t2, off);
                }
                if (lane == 0) {
                    sC1[s] = t1;
                    sIV[s] = 1.0f / (t2 - t1 + EPSF);
                }
            }
        }
    }
    __syncthreads();

    const float sharp = expf(lsharp[hh]);
    const float invT = 1.0f / (float)TT;

#pragma unroll 4
    for (int s = 0; s < CL; s++) {
        float kqA = sK[s * HD + qA];
        float kqB = sK[s * HD + qB];
        float pA0 = 0.f, pA1 = 0.f, pB0 = 0.f, pB1 = 0.f;
#pragma unroll
        for (int j4 = 0; j4 < 2; j4++) {
            float4 vv = *(const float4*)&sV2[s * HD + p0 + j4 * 4];
            float4 mm = *(const float4*)&sM02[s * HD + p0 + j4 * 4];
            float4 qv = *(const float4*)&sQ2[s * HD + p0 + j4 * 4];
#define STEP(comp, jj, PA, PB) { \
            A[jj]  += fexp2(fmaf(vv.comp, kqA, mm.comp)); \
            PA = fmaf(qv.comp, flog2(A[jj]), PA); \
            Bq[jj] += fexp2(fmaf(vv.comp, kqB, mm.comp)); \
            PB = fmaf(qv.comp, flog2(Bq[jj]), PB); }
            STEP(x, j4 * 4 + 0, pA0, pB0)
            STEP(y, j4 * 4 + 1, pA1, pB1)
            STEP(z, j4 * 4 + 2, pA0, pB0)
            STEP(w, j4 * 4 + 3, pA1, pB1)
#undef STEP
        }
        float partA = pA0 + pA1;
        float partB = pB0 + pB1;
        partA += __shfl_xor(partA, 8);
        partA += __shfl_xor(partA, 16);
        partA += __shfl_xor(partA, 32);
        partB += __shfl_xor(partB, 8);
        partB += __shfl_xor(partB, 16);
        partB += __shfl_xor(partB, 32);

        float c1v = sC1[s], iv = sIV[s];
        int tg = c * CL + s;
        float scale = (float)(tg + 1) * invT;
        float yA = (partA - c1v) * iv;
        float yB = (partB - c1v) * iv;
        float oA = copysignf(fexp2(sharp * flog2(fabsf(yA))), yA) * scale;
        float oB = copysignf(fexp2(sharp * flog2(fabsf(yB))), yB) * scale;
        if (g == 0) {
            ushort_t* yrow = Ymb + ((size_t)(bb * TT + tg)) * DIM + hh * HD;
            yrow[qA] = f2bf(oA);
            yrow[qB] = f2bf(oB);
        }
    }
}

// ---------------- Kernel 5: output projection, LDS-staged MFMA (bf16) ---------
// 32x32 tile, 4 waves (2x2 wave grid), grid (16,64)=1024 -> 4 blocks/CU.
__launch_bounds__(256)
__global__ void k_gemm_out(const ushort_t* __restrict__ Ymb, const ushort_t* __restrict__ wTo,
                           const float* __restrict__ bias, float* __restrict__ out)
{
    const int colBase = blockIdx.x * 32;
    const int rowBase = blockIdx.y * 32;

    __shared__ __align__(16) ushort_t sA[2][1024];   // 32 rows x 32 k
    __shared__ __align__(16) ushort_t sB[2][1024];   // 32 cols x 32 k

    const int tid = threadIdx.x;
    const int l = tid & 63, wv = tid >> 6;
    const int m = l & 15, g = l >> 4;
    const int wr = wv & 1, wc = wv >> 1;

    const int st = tid & 127;
    const int rl = st >> 2, cc = st & 3;
    const int ci = ((rl >> 4) * 64 + cc * 16 + (rl & 15)) * 8;
    const bool isA = tid < 128;
    const ushort_t* gp = isA ? (Ymb + (size_t)(rowBase + rl) * DIM + cc * 8)
                             : (wTo + (size_t)(colBase + rl) * DIM + cc * 8);
    ushort_t* sd0 = isA ? &sA[0][ci] : &sB[0][ci];
    ushort_t* sd1 = isA ? &sA[1][ci] : &sB[1][ci];

    f32x4 acc = {0, 0, 0, 0};

    {
        bf16x8 v = *(const bf16x8*)gp;
        *(bf16x8*)sd0 = v;
    }
    __syncthreads();

    for (int it = 0; it < 16; ++it) {
        const int cur = it & 1;
        bf16x8 nv;
        if (it < 15) nv = *(const bf16x8*)(gp + (it + 1) * 32);
        bf16x8 a = *(const bf16x8*)&sA[cur][(wr * 64 + l) * 8];
        bf16x8 b = *(const bf16x8*)&sB[cur][(wc * 64 + l) * 8];
        acc = __builtin_amdgcn_mfma_f32_16x16x32_bf16(a, b, acc, 0, 0, 0);
        if (it < 15) {
            ushort_t* sd = (cur ^ 1) ? sd1 : sd0;
            *(bf16x8*)sd = nv;
            __syncthreads();
        }
    }

    int c = colBase + wc * 16 + m;
    float bval = bias[c];
#pragma unroll
    for (int r = 0; r < 4; r++) {
        int rr = rowBase + wr * 16 + g * 4 + r;
        out[(size_t)rr * DIM + c] = acc[r] + bval;
    }
}

extern "C" void kernel_launch(void* const* d_in, const int* in_sizes, int n_in,
                              void* d_out, int out_size, void* d_ws, size_t ws_size,
                              hipStream_t stream)
{
    const float* x  = (const float*)d_in[0];
    const float* wq = (const float*)d_in[1];
    const float* bq = (const float*)d_in[2];
    const float* wk = (const float*)d_in[3];
    const float* bk = (const float*)d_in[4];
    const float* wv = (const float*)d_in[5];
    const float* bv = (const float*)d_in[6];
    const float* wo = (const float*)d_in[7];
    const float* bo = (const float*)d_in[8];
    const float* lb = (const float*)d_in[9];
    const float* lt = (const float*)d_in[10];
    const float* ls = (const float*)d_in[11];

    const int B  = in_sizes[0] / (TT * DIM);   // 2
    const int BH = B * NH;                     // 16

    float* ws = (float*)d_ws;
    const size_t nQ = (size_t)BH * TT * HD;      // 1,048,576 floats
    float* Qf2 = ws;
    float* Kf  = Qf2 + nQ;
    float* Vv2 = Kf + nQ;
    float* region = Vv2 + nQ;                    // phase-aliased region

    // phase 1-2 (cvt + qkv): bf16 staging lives in region
    ushort_t* xh  = (ushort_t*)region;                                  // B*TT*DIM bf16
    ushort_t* xl  = xh + (size_t)B * TT * DIM;
    ushort_t* wTh = (ushort_t*)(region + (size_t)B * TT * DIM);         // 3*DIM*DIM bf16
    ushort_t* wTl = wTh + (size_t)3 * DIM * DIM;
    // phase 3+ : scan state overwrites the staging area
    ushort_t* Ymb = (ushort_t*)region;                                  // B*TT*DIM bf16
    float* aA  = region + (size_t)B * TT * DIM;                         // BH*CH*4096
    float* aD  = aA  + (size_t)BH * CH * 4096;
    float* aCM = aD  + (size_t)BH * CH * HD;
    ushort_t* wTo = (ushort_t*)(aCM + (size_t)BH * CH * HD);            // persists to end

    k_cvt<<<NXB + 128, 256, 0, stream>>>(x, xh, xl, wq, wk, wv, wo, wTh, wTl, wTo);

    dim3 g1(NH, (B * TT) / 64, 3);
    k_gemm_qkv<<<g1, 256, 0, stream>>>(xh, xl, wTh, wTl, bq, bk, bv, lb, lt, Qf2, Kf, Vv2);

    dim3 g2(CH * 2, NH, B);
    k_chunk_reduce<<<g2, 256, 0, stream>>>(Kf, Vv2, aA, aD, aCM);

    int ntot = BH * 1024 + 2 * BH * 16;
    k_scan_agg<<<(ntot + 255) / 256, 256, 0, stream>>>(aA, aD, aCM, BH);

    dim3 g4(CH, NH, B);
    k_chunk_out<<<g4, 256, 0, stream>>>(Kf, Vv2, Qf2, aA, aD, aCM, ls, Ymb);

    dim3 g6(DIM / 32, (B * TT) / 32);
    k_gemm_out<<<g6, 256, 0, stream>>>(Ymb, wTo, bo, (float*)d_out);
}

// Round 21
// 86.263 us; speedup vs baseline: 1.1175x; 1.0016x over previous
//
#include <hip/hip_runtime.h>
#include <hip/hip_bf16.h>
#include <math.h>

#define DIM 512
#define NH 8
#define HD 64
#define TT 1024
#define CH 64      // chunks per (b,h) sequence
#define CL 16      // chunk length (CH*CL == TT)
#define EPSF 1e-5f
#define LN2F 0.69314718056f
#define LOG2EF 1.44269504089f

typedef unsigned short ushort_t;
typedef __attribute__((ext_vector_type(8))) short bf16x8;
typedef __attribute__((ext_vector_type(4))) float f32x4;

// raw gfx950 hardware transcendentals: v_exp_f32 = 2^x, v_log_f32 = log2(x)
__device__ __forceinline__ float fexp2(float x) { return __builtin_amdgcn_exp2f(x); }
__device__ __forceinline__ float flog2(float x) { return __builtin_amdgcn_logf(x); }

__device__ __forceinline__ ushort_t f2bf(float f) {
    union { float f; unsigned u; } v; v.f = f;
    unsigned r = v.u + 0x7FFFu + ((v.u >> 16) & 1u);
    return (ushort_t)(r >> 16);
}
__device__ __forceinline__ float bf2f(ushort_t h) {
    union { unsigned u; float f; } v; v.u = ((unsigned)h) << 16;
    return v.f;
}

// ---------------- fused cvt: x -> bf16 hi/lo  AND  weights -> bf16 [n][k] -----
#define NXB 1024   // (B*TT*DIM)/1024 with B=2
__launch_bounds__(256)
__global__ void k_cvt(const float* __restrict__ x, ushort_t* __restrict__ xh,
                      ushort_t* __restrict__ xl,
                      const float* __restrict__ wq, const float* __restrict__ wk,
                      const float* __restrict__ wv, const float* __restrict__ wo,
                      ushort_t* __restrict__ wTh, ushort_t* __restrict__ wTl,
                      ushort_t* __restrict__ wTo)
{
    if (blockIdx.x < NXB) {
        int i = (blockIdx.x * 256 + threadIdx.x) * 4;
        float4 v = *(const float4*)&x[i];
        ushort4 h, l;
        h.x = f2bf(v.x); l.x = f2bf(v.x - bf2f(h.x));
        h.y = f2bf(v.y); l.y = f2bf(v.y - bf2f(h.y));
        h.z = f2bf(v.z); l.z = f2bf(v.z - bf2f(h.z));
        h.w = f2bf(v.w); l.w = f2bf(v.w - bf2f(h.w));
        *(ushort4*)&xh[i] = h;
        *(ushort4*)&xl[i] = l;
        return;
    }
    const int bid = blockIdx.x - NXB;
    const int mat = bid >> 5;
    const int rest = bid & 31;
    const int ky = rest >> 3, nx = rest & 7;
    const float* w = (mat == 0) ? wq : (mat == 1) ? wk : (mat == 2) ? wv : wo;
    const int n  = nx * 64 + (threadIdx.x & 63);
    const int k0 = ky * 128 + (threadIdx.x >> 6) * 32;

    ushort_t hb[32], lb[32];
#pragma unroll
    for (int j = 0; j < 32; j++) {
        float v = w[(size_t)(k0 + j) * DIM + n];
        hb[j] = f2bf(v);
        lb[j] = f2bf(v - bf2f(hb[j]));
    }
    if (mat < 3) {
        ushort_t* dh = wTh + (size_t)mat * DIM * DIM + (size_t)n * DIM + k0;
        ushort_t* dl = wTl + (size_t)mat * DIM * DIM + (size_t)n * DIM + k0;
#pragma unroll
        for (int j = 0; j < 8; j++) {
            ushort4 th = { hb[4*j], hb[4*j+1], hb[4*j+2], hb[4*j+3] };
            ushort4 tl = { lb[4*j], lb[4*j+1], lb[4*j+2], lb[4*j+3] };
            *(ushort4*)&dh[4*j] = th;
            *(ushort4*)&dl[4*j] = tl;
        }
    } else {
        ushort_t* dh = wTo + (size_t)n * DIM + k0;
#pragma unroll
        for (int j = 0; j < 8; j++) {
            ushort4 th = { hb[4*j], hb[4*j+1], hb[4*j+2], hb[4*j+3] };
            *(ushort4*)&dh[4*j] = th;
        }
    }
}

// ---------------- Kernel 1: QKV projection, LDS-staged MFMA (hi/lo bf16) -----
// 2x2 wave tiling: wave (wr,wc) computes 32 rows x 32 cols (2x2 16x16 frags).
__launch_bounds__(256, 4)
__global__ void k_gemm_qkv(const ushort_t* __restrict__ xh, const ushort_t* __restrict__ xl,
                           const ushort_t* __restrict__ wTh, const ushort_t* __restrict__ wTl,
                           const float* __restrict__ bq, const float* __restrict__ bk,
                           const float* __restrict__ bv,
                           const float* __restrict__ lbeta, const float* __restrict__ ltemp,
                           float* __restrict__ Qf2, float* __restrict__ Kf,
                           float* __restrict__ Vv2)
{
    const int z = blockIdx.z, h = blockIdx.x;
    const int rowBase = blockIdx.y * 64;
    const int colBase = h * 64;
    const float* bias = (z == 0) ? bq : (z == 1) ? bk : bv;

    __shared__ __align__(16) ushort_t lds[2][4][2048];

    const int tid = threadIdx.x;
    const int l = tid & 63, wv = tid >> 6;
    const int m = l & 15, g = l >> 4;
    const int wr = wv & 1, wc = wv >> 1;

    const int rl = tid >> 2, cc = tid & 3;
    const int ci = ((rl >> 4) * 64 + cc * 16 + (rl & 15)) * 8;
    const ushort_t* gAh = xh + (size_t)(rowBase + rl) * DIM + cc * 8;
    const ushort_t* gAl = xl + (size_t)(rowBase + rl) * DIM + cc * 8;
    const ushort_t* gBh = wTh + (size_t)z * DIM * DIM + (size_t)(colBase + rl) * DIM + cc * 8;
    const ushort_t* gBl = wTl + (size_t)z * DIM * DIM + (size_t)(colBase + rl) * DIM + cc * 8;

    f32x4 acc[2][2] = { { {0,0,0,0}, {0,0,0,0} }, { {0,0,0,0}, {0,0,0,0} } };

    {
        bf16x8 a0 = *(const bf16x8*)gAh;
        bf16x8 a1 = *(const bf16x8*)gAl;
        bf16x8 b0 = *(const bf16x8*)gBh;
        bf16x8 b1 = *(const bf16x8*)gBl;
        *(bf16x8*)&lds[0][0][ci] = a0;
        *(bf16x8*)&lds[0][1][ci] = a1;
        *(bf16x8*)&lds[0][2][ci] = b0;
        *(bf16x8*)&lds[0][3][ci] = b1;
    }
    __syncthreads();

    for (int it = 0; it < 16; ++it) {
        const int cur = it & 1;
        bf16x8 nAh, nAl, nBh, nBl;
        if (it < 15) {
            const int K = (it + 1) * 32;
            nAh = *(const bf16x8*)(gAh + K);
            nAl = *(const bf16x8*)(gAl + K);
            nBh = *(const bf16x8*)(gBh + K);
            nBl = *(const bf16x8*)(gBl + K);
        }
        bf16x8 ah[2], al[2], bh[2], bl[2];
#pragma unroll
        for (int rf = 0; rf < 2; rf++) {
            ah[rf] = *(const bf16x8*)&lds[cur][0][((wr * 2 + rf) * 64 + l) * 8];
            al[rf] = *(const bf16x8*)&lds[cur][1][((wr * 2 + rf) * 64 + l) * 8];
        }
#pragma unroll
        for (int cf = 0; cf < 2; cf++) {
            bh[cf] = *(const bf16x8*)&lds[cur][2][((wc * 2 + cf) * 64 + l) * 8];
            bl[cf] = *(const bf16x8*)&lds[cur][3][((wc * 2 + cf) * 64 + l) * 8];
        }
#pragma unroll
        for (int rf = 0; rf < 2; rf++)
#pragma unroll
            for (int cf = 0; cf < 2; cf++) {
                acc[rf][cf] = __builtin_amdgcn_mfma_f32_16x16x32_bf16(ah[rf], bh[cf], acc[rf][cf], 0, 0, 0);
                acc[rf][cf] = __builtin_amdgcn_mfma_f32_16x16x32_bf16(al[rf], bh[cf], acc[rf][cf], 0, 0, 0);
                acc[rf][cf] = __builtin_amdgcn_mfma_f32_16x16x32_bf16(ah[rf], bl[cf], acc[rf][cf], 0, 0, 0);
            }
        if (it < 15) {
            const int nxt = cur ^ 1;
            *(bf16x8*)&lds[nxt][0][ci] = nAh;
            *(bf16x8*)&lds[nxt][1][ci] = nAl;
            *(bf16x8*)&lds[nxt][2][ci] = nBh;
            *(bf16x8*)&lds[nxt][3][ci] = nBl;
            __syncthreads();
        }
    }

    // epilogue: C/D layout col=lane&15, row=(lane>>4)*4+reg  [m89 verified]
    if (z == 2) {
#pragma unroll
        for (int rf = 0; rf < 2; rf++)
#pragma unroll
            for (int cf = 0; cf < 2; cf++) {
                int c = wc * 32 + cf * 16 + m;
                float bval = bias[colBase + c];
#pragma unroll
                for (int r = 0; r < 4; r++) {
                    int rr = rowBase + wr * 32 + rf * 16 + g * 4 + r;
                    int bb = rr >> 10, t = rr & (TT - 1);
                    Vv2[(((size_t)(bb * NH + h)) * TT + t) * HD + c] = (acc[rf][cf][r] + bval) * LOG2EF;
                }
            }
    } else {
        float beta = expf(lbeta[h]);
        float itemp = 1.0f / expf(ltemp[h]);
        float oscale = (z == 0) ? (LN2F / beta) : (1.0f / beta);
        float* __restrict__ dst = (z == 0) ? Qf2 : Kf;
#pragma unroll
        for (int rf = 0; rf < 2; rf++)
#pragma unroll
            for (int cf = 0; cf < 2; cf++) {
                int c = wc * 32 + cf * 16 + m;
                float bval = bias[colBase + c];
#pragma unroll
                for (int r = 0; r < 4; r++) {
                    int rr = rowBase + wr * 32 + rf * 16 + g * 4 + r;
                    int bb = rr >> 10, t = rr & (TT - 1);
                    float val = (acc[rf][cf][r] + bval) * itemp;
                    float zz = beta * val;
                    // stable softplus via hw trans: ln(1+e^-|z|) = ln2*log2(1+2^(-|z|*log2e))
                    float e = fexp2(-fabsf(zz) * LOG2EF);
                    float sp = (fmaxf(zz, 0.f) + LN2F * flog2(1.0f + e)) * oscale;
                    dst[(((size_t)(bb * NH + h)) * TT + t) * HD + c] = sp;
                }
            }
    }
}

// ---------------- Kernel 2: per-chunk local sums (CL=16) ----------------
__launch_bounds__(256)
__global__ void k_chunk_reduce(const float* __restrict__ Kf, const float* __restrict__ Vv2,
                               float* __restrict__ aA, float* __restrict__ aD,
                               float* __restrict__ aCM)
{
    const int c = blockIdx.x >> 1, qh = blockIdx.x & 1;
    const int bh = blockIdx.z * NH + blockIdx.y;
    const int tid = threadIdx.x;

    __shared__ __align__(16) float sK[CL * HD];
    __shared__ __align__(16) float sV2[CL * HD];
    __shared__ __align__(16) float sM02[CL * HD];

    size_t base = ((size_t)bh * TT + (size_t)c * CL) * HD;
    const float4* K4 = (const float4*)(Kf + base);
    const float4* V4 = (const float4*)(Vv2 + base);
    {
        int f = tid;
        float4 kv = K4[f];
        ((float4*)sK)[f] = kv;
        float4 mm;
        mm.x = flog2(kv.x + EPSF); mm.y = flog2(kv.y + EPSF);
        mm.z = flog2(kv.z + EPSF); mm.w = flog2(kv.w + EPSF);
        ((float4*)sM02)[f] = mm;
        ((float4*)sV2)[f] = V4[f];
    }
    __syncthreads();

    const int p = tid & 63, qo = tid >> 6;
    const int q0 = qh * 32 + qo * 8;
    float A[8] = {};
    float AD = 0.f, cmx = 0.f;
    const bool doD = (qh == 0) && (tid < 64);

#pragma unroll
    for (int s = 0; s < CL; s++) {
        float vp = sV2[s * HD + p];
        float mp = sM02[s * HD + p];
        float4 ka = *(const float4*)&sK[s * HD + q0];
        float4 kb = *(const float4*)&sK[s * HD + q0 + 4];
        A[0] += fexp2(fmaf(vp, ka.x, mp));
        A[1] += fexp2(fmaf(vp, ka.y, mp));
        A[2] += fexp2(fmaf(vp, ka.z, mp));
        A[3] += fexp2(fmaf(vp, ka.w, mp));
        A[4] += fexp2(fmaf(vp, kb.x, mp));
        A[5] += fexp2(fmaf(vp, kb.y, mp));
        A[6] += fexp2(fmaf(vp, kb.z, mp));
        A[7] += fexp2(fmaf(vp, kb.w, mp));
        if (doD) {
            float kn = sK[s * HD + tid];
            float ke = kn + EPSF;
            AD += fexp2(kn * LOG2EF) * ke;
            cmx = fmaxf(cmx, ke);
        }
    }

    size_t abase = ((size_t)bh * CH + c) * 4096 + (size_t)p * HD + q0;
    float4 o0 = { A[0], A[1], A[2], A[3] };
    float4 o1 = { A[4], A[5], A[6], A[7] };
    *(float4*)&aA[abase] = o0;
    *(float4*)&aA[abase + 4] = o1;
    if (doD) {
        size_t dbase = ((size_t)bh * CH + c) * HD + tid;
        aD[dbase] = AD; aCM[dbase] = cmx;
    }
}

// ---------------- Kernel 3: exclusive scan of chunk aggregates (float4) -------
__global__ void k_scan_agg(float* __restrict__ aA, float* __restrict__ aD,
                           float* __restrict__ aCM, int BH)
{
    int idx = blockIdx.x * 256 + threadIdx.x;
    int nA4 = BH * 1024;          // BH*4096/4
    int nD4 = BH * 16;            // BH*64/4
    if (idx < nA4) {
        int bh = idx >> 10, pn4 = (idx & 1023) * 4;
        float4 Sr = {0.f, 0.f, 0.f, 0.f};
        for (int c = 0; c < CH; c++) {
            float* p = &aA[((size_t)bh * CH + c) * 4096 + pn4];
            float4 t = *(float4*)p;
            *(float4*)p = Sr;
            Sr.x += t.x; Sr.y += t.y; Sr.z += t.z; Sr.w += t.w;
        }
    } else if (idx < nA4 + nD4) {
        int i = idx - nA4; int bh = i >> 4, n4 = (i & 15) * 4;
        float4 Sr = {0.f, 0.f, 0.f, 0.f};
        for (int c = 0; c < CH; c++) {
            float* p = &aD[((size_t)bh * CH + c) * HD + n4];
            float4 t = *(float4*)p;
            *(float4*)p = Sr;
            Sr.x += t.x; Sr.y += t.y; Sr.z += t.z; Sr.w += t.w;
        }
    } else if (idx < nA4 + 2 * nD4) {
        int i = idx - nA4 - nD4; int bh = i >> 4, n4 = (i & 15) * 4;
        float4 r = {0.f, 0.f, 0.f, 0.f};
        for (int c = 0; c < CH; c++) {
            float* p = &aCM[((size_t)bh * CH + c) * HD + n4];
            float4 t = *(float4*)p;
            *(float4*)p = r;
            r.x = fmaxf(r.x, t.x); r.y = fmaxf(r.y, t.y);
            r.z = fmaxf(r.z, t.z); r.w = fmaxf(r.w, t.w);
        }
    }
}

// ---------------- Kernel 4: rescan + FUSED den + output Y (bf16, CL=16) -------
// round-13 proven version: 256 thr, 1 chunk/block, grid (CH,NH,B)=1024.
__launch_bounds__(256)
__global__ void k_chunk_out(const float* __restrict__ Kf, const float* __restrict__ Vv2,
                            const float* __restrict__ Qf2, const float* __restrict__ aA,
                            const float* __restrict__ aD, const float* __restrict__ aCM,
                            const float* __restrict__ lsharp, ushort_t* __restrict__ Ymb)
{
    const int c = blockIdx.x, hh = blockIdx.y, bb = blockIdx.z;
    const int bh = bb * NH + hh;
    const int tid = threadIdx.x;

    __shared__ __align__(16) float sK[CL * HD];
    __shared__ __align__(16) float sV2[CL * HD];
    __shared__ __align__(16) float sM02[CL * HD];
    __shared__ __align__(16) float sQ2[CL * HD];
    __shared__ float sC1[CL], sIV[CL];

    size_t base = ((size_t)bh * TT + (size_t)c * CL) * HD;
    const float4* K4 = (const float4*)(Kf + base);
    const float4* V4 = (const float4*)(Vv2 + base);
    const float4* Q4 = (const float4*)(Qf2 + base);
    {
        int f = tid;
        float4 kv = K4[f];
        ((float4*)sK)[f] = kv;
        float4 mm;
        mm.x = flog2(kv.x + EPSF); mm.y = flog2(kv.y + EPSF);
        mm.z = flog2(kv.z + EPSF); mm.w = flog2(kv.w + EPSF);
        ((float4*)sM02)[f] = mm;
        ((float4*)sV2)[f] = V4[f];
        ((float4*)sQ2)[f] = Q4[f];
    }
    __syncthreads();

    const int lane = tid & 63, w = tid >> 6;
    const int g = lane >> 3, qil = lane & 7;
    const int qA = w * 8 + qil, qB = qA + 32;
    const int p0 = g * 8;

    // A-state init (issue loads early)
    float A[8], Bq[8];
    size_t abase = ((size_t)bh * CH + c) * 4096;
#pragma unroll
    for (int j = 0; j < 8; j++) {
        A[j]  = aA[abase + (size_t)(p0 + j) * HD + qA];
        Bq[j] = aA[abase + (size_t)(p0 + j) * HD + qB];
    }

    // ---- fused den phase ----
    {
        size_t dofs = ((size_t)bh * CH + c) * HD + lane;
        float AD = aD[dofs], cmx = aCM[dofs];
#pragma unroll
        for (int s = 0; s < CL; s++) {
            float kn = sK[s * HD + lane];
            float ke = kn + EPSF;
            AD += fexp2(kn * LOG2EF) * ke;     // e^k * (k+eps)
            cmx = fmaxf(cmx, ke);
            if ((s & 3) == w) {
                float qn = sQ2[s * HD + lane];
                float t1 = qn * flog2(cmx);
                float t2 = qn * flog2(AD);
#pragma unroll
                for (int off = 1; off <= 32; off <<= 1) {
                    t1 += __shfl_xor(t1, off);
                    t2 += __shfl_xor(t2, off);
                }
                if (lane == 0) {
                    sC1[s] = t1;
                    sIV[s] = 1.0f / (t2 - t1 + EPSF);
                }
            }
        }
    }
    __syncthreads();

    const float sharp = expf(lsharp[hh]);
    const float invT = 1.0f / (float)TT;

#pragma unroll 4
    for (int s = 0; s < CL; s++) {
        float kqA = sK[s * HD + qA];
        float kqB = sK[s * HD + qB];
        float pA0 = 0.f, pA1 = 0.f, pB0 = 0.f, pB1 = 0.f;
#pragma unroll
        for (int j4 = 0; j4 < 2; j4++) {
            float4 vv = *(const float4*)&sV2[s * HD + p0 + j4 * 4];
            float4 mm = *(const float4*)&sM02[s * HD + p0 + j4 * 4];
            float4 qv = *(const float4*)&sQ2[s * HD + p0 + j4 * 4];
#define STEP(comp, jj, PA, PB) { \
            A[jj]  += fexp2(fmaf(vv.comp, kqA, mm.comp)); \
            PA = fmaf(qv.comp, flog2(A[jj]), PA); \
            Bq[jj] += fexp2(fmaf(vv.comp, kqB, mm.comp)); \
            PB = fmaf(qv.comp, flog2(Bq[jj]), PB); }
            STEP(x, j4 * 4 + 0, pA0, pB0)
            STEP(y, j4 * 4 + 1, pA1, pB1)
            STEP(z, j4 * 4 + 2, pA0, pB0)
            STEP(w, j4 * 4 + 3, pA1, pB1)
#undef STEP
        }
        float partA = pA0 + pA1;
        float partB = pB0 + pB1;
        partA += __shfl_xor(partA, 8);
        partA += __shfl_xor(partA, 16);
        partA += __shfl_xor(partA, 32);
        partB += __shfl_xor(partB, 8);
        partB += __shfl_xor(partB, 16);
        partB += __shfl_xor(partB, 32);

        float c1v = sC1[s], iv = sIV[s];
        int tg = c * CL + s;
        float scale = (float)(tg + 1) * invT;
        float yA = (partA - c1v) * iv;
        float yB = (partB - c1v) * iv;
        float oA = copysignf(fexp2(sharp * flog2(fabsf(yA))), yA) * scale;
        float oB = copysignf(fexp2(sharp * flog2(fabsf(yB))), yB) * scale;
        if (g == 0) {
            ushort_t* yrow = Ymb + ((size_t)(bb * TT + tg)) * DIM + hh * HD;
            yrow[qA] = f2bf(oA);
            yrow[qB] = f2bf(oB);
        }
    }
}

// ---------------- Kernel 5: output projection, LDS-staged MFMA (bf16) ---------
// 32x32 tile, 4 waves (2x2 wave grid), grid (16,64)=1024 -> 4 blocks/CU.
__launch_bounds__(256)
__global__ void k_gemm_out(const ushort_t* __restrict__ Ymb, const ushort_t* __restrict__ wTo,
                           const float* __restrict__ bias, float* __restrict__ out)
{
    const int colBase = blockIdx.x * 32;
    const int rowBase = blockIdx.y * 32;

    __shared__ __align__(16) ushort_t sA[2][1024];   // 32 rows x 32 k
    __shared__ __align__(16) ushort_t sB[2][1024];   // 32 cols x 32 k

    const int tid = threadIdx.x;
    const int l = tid & 63, wv = tid >> 6;
    const int m = l & 15, g = l >> 4;
    const int wr = wv & 1, wc = wv >> 1;

    const int st = tid & 127;
    const int rl = st >> 2, cc = st & 3;
    const int ci = ((rl >> 4) * 64 + cc * 16 + (rl & 15)) * 8;
    const bool isA = tid < 128;
    const ushort_t* gp = isA ? (Ymb + (size_t)(rowBase + rl) * DIM + cc * 8)
                             : (wTo + (size_t)(colBase + rl) * DIM + cc * 8);
    ushort_t* sd0 = isA ? &sA[0][ci] : &sB[0][ci];
    ushort_t* sd1 = isA ? &sA[1][ci] : &sB[1][ci];

    f32x4 acc = {0, 0, 0, 0};

    {
        bf16x8 v = *(const bf16x8*)gp;
        *(bf16x8*)sd0 = v;
    }
    __syncthreads();

    for (int it = 0; it < 16; ++it) {
        const int cur = it & 1;
        bf16x8 nv;
        if (it < 15) nv = *(const bf16x8*)(gp + (it + 1) * 32);
        bf16x8 a = *(const bf16x8*)&sA[cur][(wr * 64 + l) * 8];
        bf16x8 b = *(const bf16x8*)&sB[cur][(wc * 64 + l) * 8];
        acc = __builtin_amdgcn_mfma_f32_16x16x32_bf16(a, b, acc, 0, 0, 0);
        if (it < 15) {
            ushort_t* sd = (cur ^ 1) ? sd1 : sd0;
            *(bf16x8*)sd = nv;
            __syncthreads();
        }
    }

    int c = colBase + wc * 16 + m;
    float bval = bias[c];
#pragma unroll
    for (int r = 0; r < 4; r++) {
        int rr = rowBase + wr * 16 + g * 4 + r;
        out[(size_t)rr * DIM + c] = acc[r] + bval;
    }
}

extern "C" void kernel_launch(void* const* d_in, const int* in_sizes, int n_in,
                              void* d_out, int out_size, void* d_ws, size_t ws_size,
                              hipStream_t stream)
{
    const float* x  = (const float*)d_in[0];
    const float* wq = (const float*)d_in[1];
    const float* bq = (const float*)d_in[2];
    const float* wk = (const float*)d_in[3];
    const float* bk = (const float*)d_in[4];
    const float* wv = (const float*)d_in[5];
    const float* bv = (const float*)d_in[6];
    const float* wo = (const float*)d_in[7];
    const float* bo = (const float*)d_in[8];
    const float* lb = (const float*)d_in[9];
    const float* lt = (const float*)d_in[10];
    const float* ls = (const float*)d_in[11];

    const int B  = in_sizes[0] / (TT * DIM);   // 2
    const int BH = B * NH;                     // 16

    float* ws = (float*)d_ws;
    const size_t nQ = (size_t)BH * TT * HD;      // 1,048,576 floats
    float* Qf2 = ws;
    float* Kf  = Qf2 + nQ;
    float* Vv2 = Kf + nQ;
    float* region = Vv2 + nQ;                    // phase-aliased region

    // phase 1-2 (cvt + qkv): bf16 staging lives in region
    ushort_t* xh  = (ushort_t*)region;                                  // B*TT*DIM bf16
    ushort_t* xl  = xh + (size_t)B * TT * DIM;
    ushort_t* wTh = (ushort_t*)(region + (size_t)B * TT * DIM);         // 3*DIM*DIM bf16
    ushort_t* wTl = wTh + (size_t)3 * DIM * DIM;
    // phase 3+ : scan state overwrites the staging area
    ushort_t* Ymb = (ushort_t*)region;                                  // B*TT*DIM bf16
    float* aA  = region + (size_t)B * TT * DIM;                         // BH*CH*4096
    float* aD  = aA  + (size_t)BH * CH * 4096;
    float* aCM = aD  + (size_t)BH * CH * HD;
    ushort_t* wTo = (ushort_t*)(aCM + (size_t)BH * CH * HD);            // persists to end

    k_cvt<<<NXB + 128, 256, 0, stream>>>(x, xh, xl, wq, wk, wv, wo, wTh, wTl, wTo);

    dim3 g1(NH, (B * TT) / 64, 3);
    k_gemm_qkv<<<g1, 256, 0, stream>>>(xh, xl, wTh, wTl, bq, bk, bv, lb, lt, Qf2, Kf, Vv2);

    dim3 g2(CH * 2, NH, B);
    k_chunk_reduce<<<g2, 256, 0, stream>>>(Kf, Vv2, aA, aD, aCM);

    int ntot = BH * 1024 + 2 * BH * 16;
    k_scan_agg<<<(ntot + 255) / 256, 256, 0, stream>>>(aA, aD, aCM, BH);

    dim3 g4(CH, NH, B);
    k_chunk_out<<<g4, 256, 0, stream>>>(Kf, Vv2, Qf2, aA, aD, aCM, ls, Ymb);

    dim3 g6(DIM / 32, (B * TT) / 32);
    k_gemm_out<<<g6, 256, 0, stream>>>(Ymb, wTo, bo, (float*)d_out);
}